// Round 1
// baseline (1982.508 us; speedup 1.0000x reference)
//
#include <hip/hip_runtime.h>
#include <math.h>

// Problem constants
// B=1024, D=128, DH=64, H=512
// rows = B*D = 131072
// conditioner output H_c: [1024, 8192] where H_c[b, k*128+d] = h[b,d,k]

// ---------------------------------------------------------------------------
// Generic fp32 tiled GEMM with on-the-fly MADE mask applied to B.
// C[M,N] = act(A[M,K] @ (B .* mask) + bias) (optionally += )
// MASKMODE: 0=none, 1=mask0 (deg_in[k] <= deg_h[n]), 2=mask1 (deg_h[k] <= deg_h[n]),
//           3=mask_out (deg_h[k] < deg_in[n%128]); rev selects reversed deg_in.
// ---------------------------------------------------------------------------
template<int MASKMODE, bool RELU, bool ACCUM>
__global__ __launch_bounds__(256, 4)
void gemm_k(const float* __restrict__ A, const float* __restrict__ Bm,
            const float* __restrict__ bias, float* __restrict__ C,
            int M, int N, int K, int rev)
{
    __shared__ float As[16][68];   // [k][m] transposed A tile
    __shared__ float Bs[16][68];   // [k][n]

    const int tid = threadIdx.x;
    const int bn = blockIdx.x;     // N/64
    const int bm = blockIdx.y;     // M/64
    const int tx = tid & 15, ty = tid >> 4;
    const int m_base = bm * 64, n_base = bn * 64;

    float acc[4][4] = {};

    for (int k0 = 0; k0 < K; k0 += 16) {
        // load A tile 64x16 (transposed into LDS)
        {
            const int m  = tid >> 2;          // 0..63
            const int kk = (tid & 3) * 4;     // 0,4,8,12
            const float4 a4 = *reinterpret_cast<const float4*>(&A[(m_base + m) * K + k0 + kk]);
            As[kk + 0][m] = a4.x; As[kk + 1][m] = a4.y;
            As[kk + 2][m] = a4.z; As[kk + 3][m] = a4.w;
        }
        // load B tile 16x64, apply mask per element
        {
            const int kk = tid >> 4;          // 0..15
            const int nn = (tid & 15) * 4;    // 0..60
            const int gk = k0 + kk;
            const int gn = n_base + nn;
            float4 b4 = *reinterpret_cast<const float4*>(&Bm[gk * N + gn]);
            float bv[4] = {b4.x, b4.y, b4.z, b4.w};
            #pragma unroll
            for (int j = 0; j < 4; ++j) {
                const int n = gn + j;
                bool keep = true;
                if (MASKMODE == 1) {
                    const int di = rev ? (127 - gk) : gk;     // deg_in[k]
                    keep = di <= (n % 127);                   // <= deg_h[n]
                } else if (MASKMODE == 2) {
                    keep = (gk % 127) <= (n % 127);
                } else if (MASKMODE == 3) {
                    const int nd = n & 127;
                    const int di = rev ? (127 - nd) : nd;     // deg_in[n%128]
                    keep = (gk % 127) < di;
                }
                if (!keep) bv[j] = 0.f;
                Bs[kk][nn + j] = bv[j];
            }
        }
        __syncthreads();
        #pragma unroll
        for (int kk = 0; kk < 16; ++kk) {
            const float4 a4 = *reinterpret_cast<const float4*>(&As[kk][ty * 4]);
            const float4 b4 = *reinterpret_cast<const float4*>(&Bs[kk][tx * 4]);
            const float av[4] = {a4.x, a4.y, a4.z, a4.w};
            const float bv[4] = {b4.x, b4.y, b4.z, b4.w};
            #pragma unroll
            for (int i = 0; i < 4; ++i)
                #pragma unroll
                for (int j = 0; j < 4; ++j)
                    acc[i][j] += av[i] * bv[j];
        }
        __syncthreads();
    }

    #pragma unroll
    for (int i = 0; i < 4; ++i) {
        const int m = m_base + ty * 4 + i;
        #pragma unroll
        for (int j = 0; j < 4; ++j) {
            const int n = n_base + tx * 4 + j;
            float v = acc[i][j] + bias[n];
            if (RELU) v = fmaxf(v, 0.f);
            if (ACCUM) C[m * N + n] += v;
            else       C[m * N + n] = v;
        }
    }
}

// ---------------------------------------------------------------------------
// Fused dimwise MLP + exact JVP. One block = 16 rows (rows = b*128 + d).
// u[66] = [t, x[b,d], h[b,d,0..63]] ; z1 = tanh(u@W0+b0) ; t1 = (1-z1^2)*W0[1,:]
// pre2 = z1@W1+b1 ; tpre2 = t1@W1 ; z2 = tanh(pre2) ; dz2 = (1-z2^2)*tpre2
// y = z2@W2+b2 ; jac = dz2@W2
// ---------------------------------------------------------------------------
__global__ __launch_bounds__(256, 2)
void dimwise_k(const float* __restrict__ Hc, const float* __restrict__ x,
               const float* __restrict__ t,
               const float* __restrict__ W0, const float* __restrict__ b0,
               const float* __restrict__ W1, const float* __restrict__ b1,
               const float* __restrict__ W2, const float* __restrict__ b2,
               float* __restrict__ out)
{
    __shared__ float smem[16384];        // 64 KB
    float* UT = smem;                    // [66][16]  (phase 0/1 only)
    float* zA = smem;                    // [16][512] (phase 2+, overwrites UT)
    float* tA = smem + 8192;             // [16][512]

    const int tid  = threadIdx.x;
    const int row0 = blockIdx.x * 16;    // global row = b*128 + d
    const int b    = row0 >> 7;
    const int d0   = row0 & 127;

    // ---- phase 0: build UT[k][dd], k in [0,66) ----
    if (tid < 16)       UT[1 * 16 + tid]        = x[b * 128 + d0 + tid];
    else if (tid < 32)  UT[0 * 16 + (tid - 16)] = t[0];
    #pragma unroll
    for (int it = 0; it < 4; ++it) {
        const int idx = tid + it * 256;       // 0..1023
        const int kk = idx >> 4, dd = idx & 15;
        UT[(2 + kk) * 16 + dd] = Hc[b * 8192 + kk * 128 + d0 + dd];
    }
    __syncthreads();

    // ---- phase 1: z1 / t1 for columns j = tid, tid+256; all 16 rows ----
    float accz[2][16] = {};
    for (int k = 0; k < 66; ++k) {
        const float w0a = W0[k * 512 + tid];
        const float w0b = W0[k * 512 + tid + 256];
        #pragma unroll
        for (int r4 = 0; r4 < 4; ++r4) {
            const float4 u4 = *reinterpret_cast<const float4*>(&UT[k * 16 + r4 * 4]);
            const float uv[4] = {u4.x, u4.y, u4.z, u4.w};
            #pragma unroll
            for (int i = 0; i < 4; ++i) {
                accz[0][r4 * 4 + i] += uv[i] * w0a;
                accz[1][r4 * 4 + i] += uv[i] * w0b;
            }
        }
    }
    const float b0a = b0[tid], b0b = b0[tid + 256];
    const float wxa = W0[512 + tid], wxb = W0[512 + tid + 256];   // W0 row 1 (x slot)
    __syncthreads();   // UT fully consumed; safe to overwrite smem
    #pragma unroll
    for (int r = 0; r < 16; ++r) {
        const float z_a = tanhf(accz[0][r] + b0a);
        const float z_b = tanhf(accz[1][r] + b0b);
        zA[r * 512 + tid]       = z_a;
        zA[r * 512 + tid + 256] = z_b;
        tA[r * 512 + tid]       = (1.f - z_a * z_a) * wxa;
        tA[r * 512 + tid + 256] = (1.f - z_b * z_b) * wxb;
    }
    __syncthreads();

    // ---- phase 2: layer-1 GEMM for value + tangent paths ----
    const int wv   = tid >> 6;        // wave id 0..3
    const int lane = tid & 63;
    const int r0   = wv * 4;          // 4 rows per wave
    const int j0   = lane * 8;        // 8 cols per lane

    float accp[4][8] = {};            // pre2
    float acct[4][8] = {};            // tpre2
    for (int k = 0; k < 512; k += 4) {
        float za[4][4], ta[4][4];
        #pragma unroll
        for (int r = 0; r < 4; ++r) {
            const float4 z4 = *reinterpret_cast<const float4*>(&zA[(r0 + r) * 512 + k]);
            const float4 t4 = *reinterpret_cast<const float4*>(&tA[(r0 + r) * 512 + k]);
            za[r][0] = z4.x; za[r][1] = z4.y; za[r][2] = z4.z; za[r][3] = z4.w;
            ta[r][0] = t4.x; ta[r][1] = t4.y; ta[r][2] = t4.z; ta[r][3] = t4.w;
        }
        #pragma unroll
        for (int kk = 0; kk < 4; ++kk) {
            const float4 wA = *reinterpret_cast<const float4*>(&W1[(k + kk) * 512 + j0]);
            const float4 wB = *reinterpret_cast<const float4*>(&W1[(k + kk) * 512 + j0 + 4]);
            const float w8[8] = {wA.x, wA.y, wA.z, wA.w, wB.x, wB.y, wB.z, wB.w};
            #pragma unroll
            for (int r = 0; r < 4; ++r)
                #pragma unroll
                for (int j = 0; j < 8; ++j) {
                    accp[r][j] += za[r][kk] * w8[j];
                    acct[r][j] += ta[r][kk] * w8[j];
                }
        }
    }

    // ---- phase 3: tanh/JVP epilogue + 512->1 dot, wave reduction ----
    float py[4] = {}, pj[4] = {};
    {
        const float4 w2a = *reinterpret_cast<const float4*>(&W2[j0]);
        const float4 w2b = *reinterpret_cast<const float4*>(&W2[j0 + 4]);
        const float w2[8] = {w2a.x, w2a.y, w2a.z, w2a.w, w2b.x, w2b.y, w2b.z, w2b.w};
        const float4 b1a = *reinterpret_cast<const float4*>(&b1[j0]);
        const float4 b1b = *reinterpret_cast<const float4*>(&b1[j0 + 4]);
        const float bb[8] = {b1a.x, b1a.y, b1a.z, b1a.w, b1b.x, b1b.y, b1b.z, b1b.w};
        #pragma unroll
        for (int r = 0; r < 4; ++r)
            #pragma unroll
            for (int j = 0; j < 8; ++j) {
                const float z2  = tanhf(accp[r][j] + bb[j]);
                const float dz2 = (1.f - z2 * z2) * acct[r][j];
                py[r] += z2  * w2[j];
                pj[r] += dz2 * w2[j];
            }
    }
    #pragma unroll
    for (int off = 32; off > 0; off >>= 1) {
        #pragma unroll
        for (int r = 0; r < 4; ++r) {
            py[r] += __shfl_xor(py[r], off);
            pj[r] += __shfl_xor(pj[r], off);
        }
    }
    if (lane == 0) {
        const float bias2 = b2[0];
        #pragma unroll
        for (int r = 0; r < 4; ++r) {
            const int rho = row0 + r0 + r;
            out[rho]          = py[r] + bias2;
            out[131072 + rho] = pj[r];
        }
    }
}

// ---------------------------------------------------------------------------
extern "C" void kernel_launch(void* const* d_in, const int* in_sizes, int n_in,
                              void* d_out, int out_size, void* d_ws, size_t ws_size,
                              hipStream_t stream)
{
    (void)in_sizes; (void)n_in; (void)out_size; (void)ws_size;

    const float* t     = (const float*)d_in[0];
    const float* x     = (const float*)d_in[1];
    const float* m1_W0 = (const float*)d_in[2];
    const float* m1_b0 = (const float*)d_in[3];
    const float* m1_W1 = (const float*)d_in[4];
    const float* m1_b1 = (const float*)d_in[5];
    const float* m1_W2 = (const float*)d_in[6];
    const float* m1_b2 = (const float*)d_in[7];
    const float* m2_W0 = (const float*)d_in[8];
    const float* m2_b0 = (const float*)d_in[9];
    const float* m2_W1 = (const float*)d_in[10];
    const float* m2_b1 = (const float*)d_in[11];
    const float* m2_W2 = (const float*)d_in[12];
    const float* m2_b2 = (const float*)d_in[13];
    const float* d_W0  = (const float*)d_in[14];
    const float* d_b0  = (const float*)d_in[15];
    const float* d_W1  = (const float*)d_in[16];
    const float* d_b1  = (const float*)d_in[17];
    const float* d_W2  = (const float*)d_in[18];
    const float* d_b2  = (const float*)d_in[19];

    float* ws = (float*)d_ws;
    float* h1 = ws;                   // 1024*512
    float* h2 = ws + 524288;          // 1024*512
    float* Hc = ws + 1048576;         // 1024*8192

    const dim3 blk(256);

    // net 1 (forward degrees)
    gemm_k<1, true,  false><<<dim3(8, 16),   blk, 0, stream>>>(x,  m1_W0, m1_b0, h1, 1024, 512,  128, 0);
    gemm_k<2, true,  false><<<dim3(8, 16),   blk, 0, stream>>>(h1, m1_W1, m1_b1, h2, 1024, 512,  512, 0);
    gemm_k<3, false, false><<<dim3(128, 16), blk, 0, stream>>>(h2, m1_W2, m1_b2, Hc, 1024, 8192, 512, 0);
    // net 2 (reversed degrees)
    gemm_k<1, true,  false><<<dim3(8, 16),   blk, 0, stream>>>(x,  m2_W0, m2_b0, h1, 1024, 512,  128, 1);
    gemm_k<2, true,  false><<<dim3(8, 16),   blk, 0, stream>>>(h1, m2_W1, m2_b1, h2, 1024, 512,  512, 1);
    gemm_k<3, false, true ><<<dim3(128, 16), blk, 0, stream>>>(h2, m2_W2, m2_b2, Hc, 1024, 8192, 512, 1);

    // fused dimwise MLP + exact JVP
    dimwise_k<<<dim3(131072 / 16), blk, 0, stream>>>(Hc, x, t,
                                                     d_W0, d_b0, d_W1, d_b1, d_W2, d_b2,
                                                     (float*)d_out);
}

// Round 2
// 665.870 us; speedup vs baseline: 2.9773x; 2.9773x over previous
//
#include <hip/hip_runtime.h>
#include <math.h>

// B=1024, D=128, DH=64, H=512 ; rows = B*D = 131072
// Hc: [1024, 8192] with Hc[b, k*128+d] = h[b,d,k]

typedef __attribute__((ext_vector_type(8))) short bf16x8;
typedef __attribute__((ext_vector_type(4))) float f32x4;

static __device__ __forceinline__ unsigned short f2bf(float f) {
    unsigned u = __builtin_bit_cast(unsigned, f);
    unsigned r = (u + 0x7FFFu + ((u >> 16) & 1u)) >> 16;
    return (unsigned short)r;
}

// ---------------------------------------------------------------------------
// fp32 tiled GEMM with on-the-fly MADE mask applied to B (unchanged from r1).
// ---------------------------------------------------------------------------
template<int MASKMODE, bool RELU, bool ACCUM>
__global__ __launch_bounds__(256, 4)
void gemm_k(const float* __restrict__ A, const float* __restrict__ Bm,
            const float* __restrict__ bias, float* __restrict__ C,
            int M, int N, int K, int rev)
{
    __shared__ float As[16][68];
    __shared__ float Bs[16][68];

    const int tid = threadIdx.x;
    const int bn = blockIdx.x;
    const int bm = blockIdx.y;
    const int tx = tid & 15, ty = tid >> 4;
    const int m_base = bm * 64, n_base = bn * 64;

    float acc[4][4] = {};

    for (int k0 = 0; k0 < K; k0 += 16) {
        {
            const int m  = tid >> 2;
            const int kk = (tid & 3) * 4;
            const float4 a4 = *reinterpret_cast<const float4*>(&A[(m_base + m) * K + k0 + kk]);
            As[kk + 0][m] = a4.x; As[kk + 1][m] = a4.y;
            As[kk + 2][m] = a4.z; As[kk + 3][m] = a4.w;
        }
        {
            const int kk = tid >> 4;
            const int nn = (tid & 15) * 4;
            const int gk = k0 + kk;
            const int gn = n_base + nn;
            float4 b4 = *reinterpret_cast<const float4*>(&Bm[gk * N + gn]);
            float bv[4] = {b4.x, b4.y, b4.z, b4.w};
            #pragma unroll
            for (int j = 0; j < 4; ++j) {
                const int n = gn + j;
                bool keep = true;
                if (MASKMODE == 1) {
                    const int di = rev ? (127 - gk) : gk;
                    keep = di <= (n % 127);
                } else if (MASKMODE == 2) {
                    keep = (gk % 127) <= (n % 127);
                } else if (MASKMODE == 3) {
                    const int nd = n & 127;
                    const int di = rev ? (127 - nd) : nd;
                    keep = (gk % 127) < di;
                }
                if (!keep) bv[j] = 0.f;
                Bs[kk][nn + j] = bv[j];
            }
        }
        __syncthreads();
        #pragma unroll
        for (int kk = 0; kk < 16; ++kk) {
            const float4 a4 = *reinterpret_cast<const float4*>(&As[kk][ty * 4]);
            const float4 b4 = *reinterpret_cast<const float4*>(&Bs[kk][tx * 4]);
            const float av[4] = {a4.x, a4.y, a4.z, a4.w};
            const float bv[4] = {b4.x, b4.y, b4.z, b4.w};
            #pragma unroll
            for (int i = 0; i < 4; ++i)
                #pragma unroll
                for (int j = 0; j < 4; ++j)
                    acc[i][j] += av[i] * bv[j];
        }
        __syncthreads();
    }

    #pragma unroll
    for (int i = 0; i < 4; ++i) {
        const int m = m_base + ty * 4 + i;
        #pragma unroll
        for (int j = 0; j < 4; ++j) {
            const int n = n_base + tx * 4 + j;
            float v = acc[i][j] + bias[n];
            if (RELU) v = fmaxf(v, 0.f);
            if (ACCUM) C[m * N + n] += v;
            else       C[m * N + n] = v;
        }
    }
}

// ---------------------------------------------------------------------------
// Transpose W1 [512 k][512 n] f32 -> W1p [512 n][512 k] bf16
// ---------------------------------------------------------------------------
__global__ __launch_bounds__(256, 4)
void prep_w1_k(const float* __restrict__ W1, unsigned short* __restrict__ W1p)
{
    __shared__ float tile[32][33];
    const int tid = threadIdx.x;
    const int k0 = blockIdx.y * 32, n0 = blockIdx.x * 32;
    const int c = tid & 31, r4 = tid >> 5;           // r4: 0..7
    #pragma unroll
    for (int i = 0; i < 4; ++i) {
        const int r = r4 * 4 + i;
        tile[r][c] = W1[(k0 + r) * 512 + n0 + c];
    }
    __syncthreads();
    #pragma unroll
    for (int i = 0; i < 4; ++i) {
        const int r = r4 * 4 + i;                    // row of output (n)
        W1p[(n0 + r) * 512 + k0 + c] = f2bf(tile[c][r]);
    }
}

// ---------------------------------------------------------------------------
// Fused dimwise MLP + exact JVP, layer-1 on bf16 MFMA.
// Block = 32 rows (2 M-tiles of 16) x 512 threads (8 waves).
// LDS layout (bf16, MFMA-A subtiled): zA[mt][kb][row16][8], kb-stride 272 B.
// ---------------------------------------------------------------------------
__global__ __launch_bounds__(512, 2)
void dimwise_k(const float* __restrict__ Hc, const float* __restrict__ x,
               const float* __restrict__ t, const unsigned short* __restrict__ W1p,
               const float* __restrict__ W0, const float* __restrict__ b0,
               const float* __restrict__ b1,
               const float* __restrict__ W2, const float* __restrict__ b2,
               float* __restrict__ out)
{
    __shared__ __align__(16) char smem[69632];   // zA: [0,34816) tA: [34816,69632)
    float* UT = (float*)smem;                    // [66][36] f32, phases 0-1 only

    const int tid  = threadIdx.x;
    const int row0 = blockIdx.x * 32;
    const int b    = row0 >> 7;
    const int d0   = row0 & 127;

    // ---- phase 0: UT[k][r], k in [0,66), r in [0,32) ----
    const float tval = t[0];
    for (int i = tid; i < 2112; i += 512) {
        const int k = i >> 5, r = i & 31;
        float v;
        if (k == 0)      v = tval;
        else if (k == 1) v = x[b * 128 + d0 + r];
        else             v = Hc[b * 8192 + (k - 2) * 128 + d0 + r];
        UT[k * 36 + r] = v;
    }
    __syncthreads();

    // ---- phase 1: z1/t1 for column j = tid, all 32 rows (fp32 VALU) ----
    float acc[32] = {};
    for (int k = 0; k < 66; ++k) {
        const float wj = W0[k * 512 + tid];
        #pragma unroll
        for (int r4 = 0; r4 < 8; ++r4) {
            const float4 u4 = *reinterpret_cast<const float4*>(&UT[k * 36 + r4 * 4]);
            acc[r4 * 4 + 0] += u4.x * wj;
            acc[r4 * 4 + 1] += u4.y * wj;
            acc[r4 * 4 + 2] += u4.z * wj;
            acc[r4 * 4 + 3] += u4.w * wj;
        }
    }
    const float bj = b0[tid];
    const float wx = W0[512 + tid];     // W0 row 1 (x slot)
    __syncthreads();                    // UT fully consumed; reuse smem as zA/tA

    {
        const int kb = tid >> 3, e2 = (tid & 7) * 2;
        #pragma unroll
        for (int r = 0; r < 32; ++r) {
            const float z = tanhf(acc[r] + bj);
            const float s = (1.f - z * z) * wx;
            const int mt = r >> 4, rr = r & 15;
            const int off = mt * 17408 + kb * 272 + rr * 16 + e2;
            *(unsigned short*)(smem + off)         = f2bf(z);
            *(unsigned short*)(smem + 34816 + off) = f2bf(s);
        }
    }
    __syncthreads();

    // ---- phase 2: layer-1 GEMM (bf16 MFMA), value + tangent paths ----
    const int lane = tid & 63;
    const int w    = tid >> 6;          // wave 0..7, owns n in [w*64, w*64+64)
    const char* __restrict__ W1pc = (const char*)W1p;

    f32x4 accp[2][4] = {};
    f32x4 acct[2][4] = {};

    const int l15 = lane & 15, l16 = lane >> 4;
    const int aoff0 = l15 * 16 + l16 * 272;         // + ks*1088 (=4*272)

    bf16x8 za0[2], ta0[2], bf0[4];
    #pragma unroll
    for (int mt = 0; mt < 2; ++mt) {
        za0[mt] = *(const bf16x8*)(smem + mt * 17408 + aoff0);
        ta0[mt] = *(const bf16x8*)(smem + 34816 + mt * 17408 + aoff0);
    }
    #pragma unroll
    for (int nt = 0; nt < 4; ++nt) {
        const size_t boff = (size_t)(w * 64 + nt * 16 + l15) * 1024 + l16 * 16;
        bf0[nt] = *(const bf16x8*)(W1pc + boff);
    }

    for (int ks = 0; ks < 16; ++ks) {
        bf16x8 za1[2], ta1[2], bf1[4];
        if (ks < 15) {
            const int aoff = aoff0 + (ks + 1) * 1088;
            #pragma unroll
            for (int mt = 0; mt < 2; ++mt) {
                za1[mt] = *(const bf16x8*)(smem + mt * 17408 + aoff);
                ta1[mt] = *(const bf16x8*)(smem + 34816 + mt * 17408 + aoff);
            }
            #pragma unroll
            for (int nt = 0; nt < 4; ++nt) {
                const size_t boff = (size_t)(w * 64 + nt * 16 + l15) * 1024
                                  + (ks + 1) * 64 + l16 * 16;
                bf1[nt] = *(const bf16x8*)(W1pc + boff);
            }
        }
        #pragma unroll
        for (int mt = 0; mt < 2; ++mt)
            #pragma unroll
            for (int nt = 0; nt < 4; ++nt) {
                accp[mt][nt] = __builtin_amdgcn_mfma_f32_16x16x32_bf16(za0[mt], bf0[nt], accp[mt][nt], 0, 0, 0);
                acct[mt][nt] = __builtin_amdgcn_mfma_f32_16x16x32_bf16(ta0[mt], bf0[nt], acct[mt][nt], 0, 0, 0);
            }
        #pragma unroll
        for (int mt = 0; mt < 2; ++mt) { za0[mt] = za1[mt]; ta0[mt] = ta1[mt]; }
        #pragma unroll
        for (int nt = 0; nt < 4; ++nt) bf0[nt] = bf1[nt];
    }

    // ---- phase 3: tanh/JVP epilogue + 512->1 dot ----
    float py[2][4] = {}, pj[2][4] = {};
    #pragma unroll
    for (int nt = 0; nt < 4; ++nt) {
        const int n = w * 64 + nt * 16 + l15;
        const float b1v = b1[n];
        const float w2v = W2[n];
        #pragma unroll
        for (int mt = 0; mt < 2; ++mt)
            #pragma unroll
            for (int e = 0; e < 4; ++e) {
                const float z2  = tanhf(accp[mt][nt][e] + b1v);
                const float dz2 = (1.f - z2 * z2) * acct[mt][nt][e];
                py[mt][e] += z2  * w2v;
                pj[mt][e] += dz2 * w2v;
            }
    }
    #pragma unroll
    for (int off = 1; off < 16; off <<= 1)
        #pragma unroll
        for (int mt = 0; mt < 2; ++mt)
            #pragma unroll
            for (int e = 0; e < 4; ++e) {
                py[mt][e] += __shfl_xor(py[mt][e], off);
                pj[mt][e] += __shfl_xor(pj[mt][e], off);
            }

    __syncthreads();                    // all waves done reading zA/tA
    float* part = (float*)smem;         // [8 w][2 mt][16 row][2]
    if (l15 == 0) {
        const int q = l16;
        #pragma unroll
        for (int mt = 0; mt < 2; ++mt)
            #pragma unroll
            for (int e = 0; e < 4; ++e) {
                const int idx = ((w * 2 + mt) * 16 + 4 * q + e) * 2;
                part[idx]     = py[mt][e];
                part[idx + 1] = pj[mt][e];
            }
    }
    __syncthreads();
    if (tid < 64) {
        const int mt = tid >> 5, row = (tid >> 1) & 15, wh = tid & 1;
        float s = 0.f;
        #pragma unroll
        for (int w8 = 0; w8 < 8; ++w8)
            s += part[((w8 * 2 + mt) * 16 + row) * 2 + wh];
        const int grow = row0 + mt * 16 + row;
        if (wh == 0) out[grow] = s + b2[0];
        else         out[131072 + grow] = s;
    }
}

// ---------------------------------------------------------------------------
extern "C" void kernel_launch(void* const* d_in, const int* in_sizes, int n_in,
                              void* d_out, int out_size, void* d_ws, size_t ws_size,
                              hipStream_t stream)
{
    (void)in_sizes; (void)n_in; (void)out_size; (void)ws_size;

    const float* t     = (const float*)d_in[0];
    const float* x     = (const float*)d_in[1];
    const float* m1_W0 = (const float*)d_in[2];
    const float* m1_b0 = (const float*)d_in[3];
    const float* m1_W1 = (const float*)d_in[4];
    const float* m1_b1 = (const float*)d_in[5];
    const float* m1_W2 = (const float*)d_in[6];
    const float* m1_b2 = (const float*)d_in[7];
    const float* m2_W0 = (const float*)d_in[8];
    const float* m2_b0 = (const float*)d_in[9];
    const float* m2_W1 = (const float*)d_in[10];
    const float* m2_b1 = (const float*)d_in[11];
    const float* m2_W2 = (const float*)d_in[12];
    const float* m2_b2 = (const float*)d_in[13];
    const float* d_W0  = (const float*)d_in[14];
    const float* d_b0  = (const float*)d_in[15];
    const float* d_W1  = (const float*)d_in[16];
    const float* d_b1  = (const float*)d_in[17];
    const float* d_W2  = (const float*)d_in[18];
    const float* d_b2  = (const float*)d_in[19];

    float* ws = (float*)d_ws;
    float* h1 = ws;                       // 1024*512  (reused for W1p after last read)
    float* h2 = ws + 524288;              // 1024*512
    float* Hc = ws + 1048576;             // 1024*8192
    unsigned short* W1p = (unsigned short*)d_ws;   // aliases h1 region (512 KB)

    const dim3 blk(256);

    // net 1 (forward degrees)
    gemm_k<1, true,  false><<<dim3(8, 16),   blk, 0, stream>>>(x,  m1_W0, m1_b0, h1, 1024, 512,  128, 0);
    gemm_k<2, true,  false><<<dim3(8, 16),   blk, 0, stream>>>(h1, m1_W1, m1_b1, h2, 1024, 512,  512, 0);
    gemm_k<3, false, false><<<dim3(128, 16), blk, 0, stream>>>(h2, m1_W2, m1_b2, Hc, 1024, 8192, 512, 0);
    // net 2 (reversed degrees)
    gemm_k<1, true,  false><<<dim3(8, 16),   blk, 0, stream>>>(x,  m2_W0, m2_b0, h1, 1024, 512,  128, 1);
    gemm_k<2, true,  false><<<dim3(8, 16),   blk, 0, stream>>>(h1, m2_W1, m2_b1, h2, 1024, 512,  512, 1);
    gemm_k<3, false, true ><<<dim3(128, 16), blk, 0, stream>>>(h2, m2_W2, m2_b2, Hc, 1024, 8192, 512, 1);

    // one-time: W1 -> bf16 transposed [n][k] into the (now dead) h1 region
    prep_w1_k<<<dim3(16, 16), blk, 0, stream>>>(d_W1, W1p);

    // fused dimwise MLP + exact JVP (layer-1 on MFMA)
    dimwise_k<<<dim3(131072 / 32), dim3(512), 0, stream>>>(Hc, x, t, W1p,
                                                           d_W0, d_b0, d_b1, d_W2, d_b2,
                                                           (float*)d_out);
}

// Round 3
// 433.598 us; speedup vs baseline: 4.5722x; 1.5357x over previous
//
#include <hip/hip_runtime.h>
#include <math.h>

// B=1024, D=128, DH=64, H=512 ; rows = B*D = 131072
// Hc planes (bf16 hi/lo): [1024, 8192], Hc[b, k*128+d] = h[b,d,k]

typedef __attribute__((ext_vector_type(8))) short bf16x8;
typedef __attribute__((ext_vector_type(4))) float f32x4;

static __device__ __forceinline__ unsigned short f2bf(float f) {
    unsigned u = __builtin_bit_cast(unsigned, f);
    unsigned r = (u + 0x7FFFu + ((u >> 16) & 1u)) >> 16;
    return (unsigned short)r;
}
static __device__ __forceinline__ float bf2f(unsigned short h) {
    unsigned u = ((unsigned)h) << 16;
    return __builtin_bit_cast(float, u);
}

// ---------------------------------------------------------------------------
// MADE layer 1 & 2, both nets in one launch. fp32 VALU (small GEMMs).
// MODE 1: x[1024,128] -> h1cat[1024,1024] f32 (relu)
// MODE 2: h1cat -> h2cat[1024,1024] bf16 (relu)
// ---------------------------------------------------------------------------
template<int MODE>
__global__ __launch_bounds__(256, 4)
void made_gemm_k(const float* __restrict__ A0,
                 const float* __restrict__ Wn1, const float* __restrict__ Wn2,
                 const float* __restrict__ bn1, const float* __restrict__ bn2,
                 void* __restrict__ Cout)
{
    constexpr int K   = (MODE == 1) ? 128 : 512;
    constexpr int LDA = (MODE == 1) ? 128 : 1024;

    __shared__ float As[16][68];
    __shared__ float Bs[16][68];

    const int tid = threadIdx.x;
    const int bn  = blockIdx.x;          // 0..15 : net = bn>>3
    const int bm  = blockIdx.y;          // 0..15
    const int net = bn >> 3;
    const int nb  = (bn & 7) * 64;       // within-net n base
    const int tx = tid & 15, ty = tid >> 4;
    const int m_base = bm * 64;

    const float* __restrict__ A  = (MODE == 2) ? (A0 + net * 512) : A0;
    const float* __restrict__ W  = net ? Wn2 : Wn1;
    const float* __restrict__ bi = net ? bn2 : bn1;

    float acc[4][4] = {};

    for (int k0 = 0; k0 < K; k0 += 16) {
        {
            const int m  = tid >> 2;
            const int kk = (tid & 3) * 4;
            const float4 a4 = *reinterpret_cast<const float4*>(&A[(size_t)(m_base + m) * LDA + k0 + kk]);
            As[kk + 0][m] = a4.x; As[kk + 1][m] = a4.y;
            As[kk + 2][m] = a4.z; As[kk + 3][m] = a4.w;
        }
        {
            const int kk = tid >> 4;
            const int nn = (tid & 15) * 4;
            const int gk = k0 + kk;
            const int gn = nb + nn;
            float4 b4 = *reinterpret_cast<const float4*>(&W[gk * 512 + gn]);
            float bv[4] = {b4.x, b4.y, b4.z, b4.w};
            #pragma unroll
            for (int j = 0; j < 4; ++j) {
                const int n = gn + j;
                bool keep;
                if (MODE == 1) keep = net ? ((127 - gk) <= (n % 127)) : (gk <= (n % 127));
                else           keep = (gk % 127) <= (n % 127);
                Bs[kk][nn + j] = keep ? bv[j] : 0.f;
            }
        }
        __syncthreads();
        #pragma unroll
        for (int kk = 0; kk < 16; ++kk) {
            const float4 a4 = *reinterpret_cast<const float4*>(&As[kk][ty * 4]);
            const float4 b4 = *reinterpret_cast<const float4*>(&Bs[kk][tx * 4]);
            const float av[4] = {a4.x, a4.y, a4.z, a4.w};
            const float bv[4] = {b4.x, b4.y, b4.z, b4.w};
            #pragma unroll
            for (int i = 0; i < 4; ++i)
                #pragma unroll
                for (int j = 0; j < 4; ++j)
                    acc[i][j] += av[i] * bv[j];
        }
        __syncthreads();
    }

    #pragma unroll
    for (int i = 0; i < 4; ++i) {
        const int m = m_base + ty * 4 + i;
        #pragma unroll
        for (int j = 0; j < 4; ++j) {
            const int n = nb + tx * 4 + j;
            float v = fmaxf(acc[i][j] + bi[n], 0.f);
            const size_t cidx = (size_t)m * 1024 + net * 512 + n;
            if (MODE == 1) ((float*)Cout)[cidx] = v;
            else           ((unsigned short*)Cout)[cidx] = f2bf(v);
        }
    }
}

// ---------------------------------------------------------------------------
// W1 [512 k][512 n] f32 -> W1p [512 n][512 k] bf16
// ---------------------------------------------------------------------------
__global__ __launch_bounds__(256, 4)
void prep_w1_k(const float* __restrict__ W1, unsigned short* __restrict__ W1p)
{
    __shared__ float tile[32][33];
    const int tid = threadIdx.x;
    const int k0 = blockIdx.y * 32, n0 = blockIdx.x * 32;
    const int c = tid & 31, r4 = tid >> 5;
    #pragma unroll
    for (int i = 0; i < 4; ++i) {
        const int r = r4 * 4 + i;
        tile[r][c] = W1[(k0 + r) * 512 + n0 + c];
    }
    __syncthreads();
    #pragma unroll
    for (int i = 0; i < 4; ++i) {
        const int r = r4 * 4 + i;
        W1p[(n0 + r) * 512 + k0 + c] = f2bf(tile[c][r]);
    }
}

// ---------------------------------------------------------------------------
// W0 h-rows -> W0t[512 n][64 k] bf16   (W0t[n][k] = W0[2+k][n])
// ---------------------------------------------------------------------------
__global__ __launch_bounds__(256, 4)
void prep_w0t_k(const float* __restrict__ W0, unsigned short* __restrict__ W0t)
{
    const int idx = blockIdx.x * 256 + threadIdx.x;   // 0..32767
    const int n = idx & 511, k = idx >> 9;
    W0t[n * 64 + k] = f2bf(W0[(2 + k) * 512 + n]);
}

// ---------------------------------------------------------------------------
// Fused MADE layer-3, both nets: Hc = h2cat[1024,1024] @ W2cat[1024,8192] + b
// bf16 MFMA; mask+cvt of W2 fused into B staging; writes bf16 hi+lo planes.
// Block 128x128, 512 threads (8 waves = 4 wm x 2 wn); BK=32, dbuf LDS B.
// ---------------------------------------------------------------------------
__global__ __launch_bounds__(512, 4)
void gemm3_k(const unsigned short* __restrict__ h2cat,
             const float* __restrict__ W2a, const float* __restrict__ W2b,
             const float* __restrict__ ba, const float* __restrict__ bb,
             unsigned short* __restrict__ Hchi, unsigned short* __restrict__ Hclo)
{
    __shared__ unsigned short Bs[2][128 * 40];   // [n][k], row stride 40 shorts (80 B)

    const int tid = threadIdx.x;
    const int n0 = blockIdx.x * 128, m0 = blockIdx.y * 128;
    const int lane = tid & 63, w = tid >> 6;
    const int l15 = lane & 15, l16 = lane >> 4;
    const int wm = w & 3, wn = w >> 2;

    const int sk = tid >> 4;          // stage: k 0..31
    const int sn = (tid & 15) * 8;    // stage: n 0..120

    f32x4 acc[2][4] = {};

    // ---- prologue stage (s=0) ----
    {
        const int gk = sk;
        const float* __restrict__ src = W2a;       // s=0 -> net 0
        const float4 v0 = *(const float4*)&src[(size_t)gk * 8192 + n0 + sn];
        const float4 v1 = *(const float4*)&src[(size_t)gk * 8192 + n0 + sn + 4];
        const float vv[8] = {v0.x, v0.y, v0.z, v0.w, v1.x, v1.y, v1.z, v1.w};
        const int km = gk % 127;
        #pragma unroll
        for (int j = 0; j < 8; ++j) {
            const int dg = sn + j;
            Bs[0][(sn + j) * 40 + sk] = (km < dg) ? f2bf(vv[j]) : (unsigned short)0;
        }
    }

    const unsigned short* Arow[2];
    #pragma unroll
    for (int mt = 0; mt < 2; ++mt)
        Arow[mt] = h2cat + (size_t)(m0 + wm * 32 + mt * 16 + l15) * 1024 + l16 * 8;

    bf16x8 a0[2];
    #pragma unroll
    for (int mt = 0; mt < 2; ++mt) a0[mt] = *(const bf16x8*)(Arow[mt]);
    __syncthreads();

    for (int s = 0; s < 32; ++s) {
        if (s < 31) {   // stage s+1 into other buffer
            const int gk = (s + 1) * 32 + sk;
            const int net = gk >> 9;
            const int krel = gk & 511;
            const float* __restrict__ src = net ? W2b : W2a;
            const float4 v0 = *(const float4*)&src[(size_t)krel * 8192 + n0 + sn];
            const float4 v1 = *(const float4*)&src[(size_t)krel * 8192 + n0 + sn + 4];
            const float vv[8] = {v0.x, v0.y, v0.z, v0.w, v1.x, v1.y, v1.z, v1.w};
            const int km = krel % 127;
            #pragma unroll
            for (int j = 0; j < 8; ++j) {
                const int dg = sn + j;
                const bool keep = net ? (km < (127 - dg)) : (km < dg);
                Bs[(s + 1) & 1][(sn + j) * 40 + sk] = keep ? f2bf(vv[j]) : (unsigned short)0;
            }
        }
        bf16x8 a1[2];
        if (s < 31) {
            #pragma unroll
            for (int mt = 0; mt < 2; ++mt)
                a1[mt] = *(const bf16x8*)(Arow[mt] + (s + 1) * 32);
        }
        const unsigned short* bsb = Bs[s & 1];
        #pragma unroll
        for (int nt = 0; nt < 4; ++nt) {
            const bf16x8 bf = *(const bf16x8*)(bsb + (wn * 64 + nt * 16 + l15) * 40 + l16 * 8);
            #pragma unroll
            for (int mt = 0; mt < 2; ++mt)
                acc[mt][nt] = __builtin_amdgcn_mfma_f32_16x16x32_bf16(a0[mt], bf, acc[mt][nt], 0, 0, 0);
        }
        #pragma unroll
        for (int mt = 0; mt < 2; ++mt) a0[mt] = a1[mt];
        __syncthreads();
    }

    #pragma unroll
    for (int nt = 0; nt < 4; ++nt) {
        const int n = n0 + wn * 64 + nt * 16 + l15;
        const float bsum = ba[n] + bb[n];
        #pragma unroll
        for (int mt = 0; mt < 2; ++mt) {
            const int mrow = m0 + wm * 32 + mt * 16 + l16 * 4;
            #pragma unroll
            for (int e = 0; e < 4; ++e) {
                const float v = acc[mt][nt][e] + bsum;
                const unsigned short hi = f2bf(v);
                Hchi[(size_t)(mrow + e) * 8192 + n] = hi;
                Hclo[(size_t)(mrow + e) * 8192 + n] = f2bf(v - bf2f(hi));
            }
        }
    }
}

// ---------------------------------------------------------------------------
// Fused dimwise MLP + exact JVP. Block = 32 rows x 512 threads (8 waves).
// Phase 1 (z1pre) now on MFMA from bf16 Hc hi/lo planes. Phase 2/3 as r2.
// LDS: zA [0,34816) tA [34816,69632) Hstage [69632,77824) xbuf [77824,77952)
// ---------------------------------------------------------------------------
__global__ __launch_bounds__(512, 4)
void dimwise_k(const unsigned short* __restrict__ Hchi, const unsigned short* __restrict__ Hclo,
               const float* __restrict__ x, const float* __restrict__ t,
               const unsigned short* __restrict__ W1p, const unsigned short* __restrict__ W0t,
               const float* __restrict__ W0, const float* __restrict__ b0,
               const float* __restrict__ b1,
               const float* __restrict__ W2, const float* __restrict__ b2,
               float* __restrict__ out)
{
    __shared__ __align__(16) char smem[77952];

    const int tid  = threadIdx.x;
    const int row0 = blockIdx.x * 32;
    const int b    = row0 >> 7;
    const int d0   = row0 & 127;

    const int lane = tid & 63;
    const int w    = tid >> 6;          // wave 0..7, owns layer-1 cols [w*64, w*64+64)
    const int l15 = lane & 15, l16 = lane >> 4;

    // ---- phase 0: stage Hc hi/lo tile [2][32 row][64 k] (XOR-swizzled) + x ----
    {
        const int plane = tid >> 8;           // 0/1
        const int rem   = tid & 255;
        const int k     = rem >> 2;           // 0..63
        const int part  = rem & 3;            // 0..3 -> d offset part*8
        const unsigned short* __restrict__ Hsrc = plane ? Hclo : Hchi;
        const bf16x8 hv = *(const bf16x8*)(Hsrc + (size_t)b * 8192 + k * 128 + d0 + part * 8);
        #pragma unroll
        for (int j = 0; j < 8; ++j) {
            const int row = part * 8 + j;
            const int byte = 69632 + plane * 4096 + row * 128 + ((2 * k) ^ ((row & 7) << 4));
            *(unsigned short*)(smem + byte) = (unsigned short)hv[j];
        }
        if (tid < 32) ((float*)(smem + 77824))[tid] = x[b * 128 + d0 + tid];
    }
    __syncthreads();

    // ---- phase 1: z1pre via MFMA (2 planes), rank-2 + tanh epilogue ----
    f32x4 zacc[2][4] = {};
    #pragma unroll
    for (int ks = 0; ks < 2; ++ks) {
        bf16x8 af[2][2];    // [plane][mt]
        #pragma unroll
        for (int plane = 0; plane < 2; ++plane)
            #pragma unroll
            for (int mt = 0; mt < 2; ++mt) {
                const int row = mt * 16 + l15;
                const int inner = (ks * 64 + l16 * 16) ^ ((l15 & 7) << 4);
                af[plane][mt] = *(const bf16x8*)(smem + 69632 + plane * 4096 + row * 128 + inner);
            }
        #pragma unroll
        for (int nt = 0; nt < 4; ++nt) {
            const int n = w * 64 + nt * 16 + l15;
            const bf16x8 bf = *(const bf16x8*)(W0t + n * 64 + ks * 32 + l16 * 8);
            #pragma unroll
            for (int plane = 0; plane < 2; ++plane)
                #pragma unroll
                for (int mt = 0; mt < 2; ++mt)
                    zacc[mt][nt] = __builtin_amdgcn_mfma_f32_16x16x32_bf16(af[plane][mt], bf, zacc[mt][nt], 0, 0, 0);
        }
    }
    {
        const float tv = t[0];
        const float* xb = (const float*)(smem + 77824);
        float xm[2][4];
        #pragma unroll
        for (int mt = 0; mt < 2; ++mt)
            #pragma unroll
            for (int e = 0; e < 4; ++e)
                xm[mt][e] = xb[mt * 16 + l16 * 4 + e];
        #pragma unroll
        for (int nt = 0; nt < 4; ++nt) {
            const int n = w * 64 + nt * 16 + l15;
            const float b0n = b0[n];
            const float w00 = W0[n];
            const float w01 = W0[512 + n];
            const int kboff = (n >> 3) * 272 + (n & 7) * 2;
            #pragma unroll
            for (int mt = 0; mt < 2; ++mt)
                #pragma unroll
                for (int e = 0; e < 4; ++e) {
                    const float pre = zacc[mt][nt][e] + b0n + tv * w00 + xm[mt][e] * w01;
                    const float z = tanhf(pre);
                    const float s = (1.f - z * z) * w01;
                    const int off = mt * 17408 + kboff + (l16 * 4 + e) * 16;
                    *(unsigned short*)(smem + off)         = f2bf(z);
                    *(unsigned short*)(smem + 34816 + off) = f2bf(s);
                }
        }
    }
    __syncthreads();

    // ---- phase 2: layer-1 GEMM (bf16 MFMA), value + tangent paths (r2) ----
    const char* __restrict__ W1pc = (const char*)W1p;

    f32x4 accp[2][4] = {};
    f32x4 acct[2][4] = {};

    const int aoff0 = l15 * 16 + l16 * 272;

    bf16x8 za0[2], ta0[2], bf0[4];
    #pragma unroll
    for (int mt = 0; mt < 2; ++mt) {
        za0[mt] = *(const bf16x8*)(smem + mt * 17408 + aoff0);
        ta0[mt] = *(const bf16x8*)(smem + 34816 + mt * 17408 + aoff0);
    }
    #pragma unroll
    for (int nt = 0; nt < 4; ++nt) {
        const size_t boff = (size_t)(w * 64 + nt * 16 + l15) * 1024 + l16 * 16;
        bf0[nt] = *(const bf16x8*)(W1pc + boff);
    }

    for (int ks = 0; ks < 16; ++ks) {
        bf16x8 za1[2], ta1[2], bf1[4];
        if (ks < 15) {
            const int aoff = aoff0 + (ks + 1) * 1088;
            #pragma unroll
            for (int mt = 0; mt < 2; ++mt) {
                za1[mt] = *(const bf16x8*)(smem + mt * 17408 + aoff);
                ta1[mt] = *(const bf16x8*)(smem + 34816 + mt * 17408 + aoff);
            }
            #pragma unroll
            for (int nt = 0; nt < 4; ++nt) {
                const size_t boff = (size_t)(w * 64 + nt * 16 + l15) * 1024
                                  + (ks + 1) * 64 + l16 * 16;
                bf1[nt] = *(const bf16x8*)(W1pc + boff);
            }
        }
        #pragma unroll
        for (int mt = 0; mt < 2; ++mt)
            #pragma unroll
            for (int nt = 0; nt < 4; ++nt) {
                accp[mt][nt] = __builtin_amdgcn_mfma_f32_16x16x32_bf16(za0[mt], bf0[nt], accp[mt][nt], 0, 0, 0);
                acct[mt][nt] = __builtin_amdgcn_mfma_f32_16x16x32_bf16(ta0[mt], bf0[nt], acct[mt][nt], 0, 0, 0);
            }
        #pragma unroll
        for (int mt = 0; mt < 2; ++mt) { za0[mt] = za1[mt]; ta0[mt] = ta1[mt]; }
        #pragma unroll
        for (int nt = 0; nt < 4; ++nt) bf0[nt] = bf1[nt];
    }

    // ---- phase 3: tanh/JVP epilogue + 512->1 dot (r2) ----
    float py[2][4] = {}, pj[2][4] = {};
    #pragma unroll
    for (int nt = 0; nt < 4; ++nt) {
        const int n = w * 64 + nt * 16 + l15;
        const float b1v = b1[n];
        const float w2v = W2[n];
        #pragma unroll
        for (int mt = 0; mt < 2; ++mt)
            #pragma unroll
            for (int e = 0; e < 4; ++e) {
                const float z2  = tanhf(accp[mt][nt][e] + b1v);
                const float dz2 = (1.f - z2 * z2) * acct[mt][nt][e];
                py[mt][e] += z2  * w2v;
                pj[mt][e] += dz2 * w2v;
            }
    }
    #pragma unroll
    for (int off = 1; off < 16; off <<= 1)
        #pragma unroll
        for (int mt = 0; mt < 2; ++mt)
            #pragma unroll
            for (int e = 0; e < 4; ++e) {
                py[mt][e] += __shfl_xor(py[mt][e], off);
                pj[mt][e] += __shfl_xor(pj[mt][e], off);
            }

    __syncthreads();
    float* part = (float*)smem;         // [8 w][2 mt][16 row][2]
    if (l15 == 0) {
        const int q = l16;
        #pragma unroll
        for (int mt = 0; mt < 2; ++mt)
            #pragma unroll
            for (int e = 0; e < 4; ++e) {
                const int idx = ((w * 2 + mt) * 16 + 4 * q + e) * 2;
                part[idx]     = py[mt][e];
                part[idx + 1] = pj[mt][e];
            }
    }
    __syncthreads();
    if (tid < 64) {
        const int mt = tid >> 5, row = (tid >> 1) & 15, wh = tid & 1;
        float s = 0.f;
        #pragma unroll
        for (int w8 = 0; w8 < 8; ++w8)
            s += part[((w8 * 2 + mt) * 16 + row) * 2 + wh];
        const int grow = row0 + mt * 16 + row;
        if (wh == 0) out[grow] = s + b2[0];
        else         out[131072 + grow] = s;
    }
}

// ---------------------------------------------------------------------------
extern "C" void kernel_launch(void* const* d_in, const int* in_sizes, int n_in,
                              void* d_out, int out_size, void* d_ws, size_t ws_size,
                              hipStream_t stream)
{
    (void)in_sizes; (void)n_in; (void)out_size; (void)ws_size;

    const float* t     = (const float*)d_in[0];
    const float* x     = (const float*)d_in[1];
    const float* m1_W0 = (const float*)d_in[2];
    const float* m1_b0 = (const float*)d_in[3];
    const float* m1_W1 = (const float*)d_in[4];
    const float* m1_b1 = (const float*)d_in[5];
    const float* m1_W2 = (const float*)d_in[6];
    const float* m1_b2 = (const float*)d_in[7];
    const float* m2_W0 = (const float*)d_in[8];
    const float* m2_b0 = (const float*)d_in[9];
    const float* m2_W1 = (const float*)d_in[10];
    const float* m2_b1 = (const float*)d_in[11];
    const float* m2_W2 = (const float*)d_in[12];
    const float* m2_b2 = (const float*)d_in[13];
    const float* d_W0  = (const float*)d_in[14];
    const float* d_b0  = (const float*)d_in[15];
    const float* d_W1  = (const float*)d_in[16];
    const float* d_b1  = (const float*)d_in[17];
    const float* d_W2  = (const float*)d_in[18];
    const float* d_b2  = (const float*)d_in[19];

    // ws layout (bytes), peak 36.2 MB:
    // [0, 512K)        W1p bf16 [512][512]
    // [512K, 576K)     W0t bf16 [512][64]
    // [576K, 2.6M)     h2cat bf16 [1024][1024]
    // [0x290000, +16M) h1cat f32 [1024][1024] (first 4MB), overlaid by Hclo
    // [0x1290000,+16M) Hchi bf16 [1024][8192]
    char* base = (char*)d_ws;
    unsigned short* W1p   = (unsigned short*)(base);
    unsigned short* W0t   = (unsigned short*)(base + 0x80000);
    unsigned short* h2cat = (unsigned short*)(base + 0x90000);
    float*          h1cat = (float*)(base + 0x290000);
    unsigned short* Hclo  = (unsigned short*)(base + 0x290000);
    unsigned short* Hchi  = (unsigned short*)(base + 0x1290000);

    prep_w1_k<<<dim3(16, 16), dim3(256), 0, stream>>>(d_W1, W1p);
    prep_w0t_k<<<dim3(128), dim3(256), 0, stream>>>(d_W0, W0t);

    made_gemm_k<1><<<dim3(16, 16), dim3(256), 0, stream>>>(x, m1_W0, m2_W0, m1_b0, m2_b0, h1cat);
    made_gemm_k<2><<<dim3(16, 16), dim3(256), 0, stream>>>(h1cat, m1_W1, m2_W1, m1_b1, m2_b1, h2cat);

    gemm3_k<<<dim3(64, 8), dim3(512), 0, stream>>>(h2cat, m1_W2, m2_W2, m1_b2, m2_b2, Hchi, Hclo);

    dimwise_k<<<dim3(4096), dim3(512), 0, stream>>>(Hchi, Hclo, x, t, W1p, W0t,
                                                    d_W0, d_b0, d_b1, d_W2, d_b2,
                                                    (float*)d_out);
}

// Round 4
// 431.038 us; speedup vs baseline: 4.5994x; 1.0059x over previous
//
#include <hip/hip_runtime.h>
#include <math.h>

// B=1024, D=128, DH=64, H=512 ; rows = B*D = 131072
// Hc (bf16): [1024, 8192], Hc[b, k*128+d] = h[b,d,k]

typedef __attribute__((ext_vector_type(8))) short bf16x8;
typedef __attribute__((ext_vector_type(4))) float f32x4;

static __device__ __forceinline__ unsigned short f2bf(float f) {
    unsigned u = __builtin_bit_cast(unsigned, f);
    unsigned r = (u + 0x7FFFu + ((u >> 16) & 1u)) >> 16;
    return (unsigned short)r;
}

static __device__ __forceinline__ float fexp2(float x) {
#if __has_builtin(__builtin_amdgcn_exp2f)
    return __builtin_amdgcn_exp2f(x);
#else
    float r; asm("v_exp_f32 %0, %1" : "=v"(r) : "v"(x)); return r;
#endif
}
static __device__ __forceinline__ float frcp(float x) {
#if __has_builtin(__builtin_amdgcn_rcpf)
    return __builtin_amdgcn_rcpf(x);
#else
    float r; asm("v_rcp_f32 %0, %1" : "=v"(r) : "v"(x)); return r;
#endif
}
// tanh(x) = 1 - 2/(1+e^{2x}); exp2-based, ~1e-6 abs err, saturates correctly.
static __device__ __forceinline__ float fast_tanh(float x) {
    const float e = fexp2(x * 2.8853900817779268f);   // e^{2x}
    const float r = frcp(1.f + e);
    return __builtin_fmaf(-2.f, r, 1.f);
}

// ---------------------------------------------------------------------------
// MADE layer 1, both nets: x[1024,128] @ (W0 .* mask1) -> h1cat bf16 [1024][1024]
// fp32 VALU (tiny K), relu, bf16 store.
// ---------------------------------------------------------------------------
__global__ __launch_bounds__(256, 4)
void made1_k(const float* __restrict__ x,
             const float* __restrict__ Wn1, const float* __restrict__ Wn2,
             const float* __restrict__ bn1, const float* __restrict__ bn2,
             unsigned short* __restrict__ h1cat)
{
    __shared__ float As[16][68];
    __shared__ float Bs[16][68];

    const int tid = threadIdx.x;
    const int bn  = blockIdx.x;          // 0..15 : net = bn>>3
    const int bm  = blockIdx.y;          // 0..15
    const int net = bn >> 3;
    const int nb  = (bn & 7) * 64;
    const int tx = tid & 15, ty = tid >> 4;
    const int m_base = bm * 64;

    const float* __restrict__ W  = net ? Wn2 : Wn1;
    const float* __restrict__ bi = net ? bn2 : bn1;

    float acc[4][4] = {};

    for (int k0 = 0; k0 < 128; k0 += 16) {
        {
            const int m  = tid >> 2;
            const int kk = (tid & 3) * 4;
            const float4 a4 = *reinterpret_cast<const float4*>(&x[(size_t)(m_base + m) * 128 + k0 + kk]);
            As[kk + 0][m] = a4.x; As[kk + 1][m] = a4.y;
            As[kk + 2][m] = a4.z; As[kk + 3][m] = a4.w;
        }
        {
            const int kk = tid >> 4;
            const int nn = (tid & 15) * 4;
            const int gk = k0 + kk;
            const int gn = nb + nn;
            float4 b4 = *reinterpret_cast<const float4*>(&W[gk * 512 + gn]);
            float bv[4] = {b4.x, b4.y, b4.z, b4.w};
            #pragma unroll
            for (int j = 0; j < 4; ++j) {
                const int n = gn + j;
                const bool keep = net ? ((127 - gk) <= (n % 127)) : (gk <= (n % 127));
                Bs[kk][nn + j] = keep ? bv[j] : 0.f;
            }
        }
        __syncthreads();
        #pragma unroll
        for (int kk = 0; kk < 16; ++kk) {
            const float4 a4 = *reinterpret_cast<const float4*>(&As[kk][ty * 4]);
            const float4 b4 = *reinterpret_cast<const float4*>(&Bs[kk][tx * 4]);
            const float av[4] = {a4.x, a4.y, a4.z, a4.w};
            const float bv[4] = {b4.x, b4.y, b4.z, b4.w};
            #pragma unroll
            for (int i = 0; i < 4; ++i)
                #pragma unroll
                for (int j = 0; j < 4; ++j)
                    acc[i][j] += av[i] * bv[j];
        }
        __syncthreads();
    }

    #pragma unroll
    for (int i = 0; i < 4; ++i) {
        const int m = m_base + ty * 4 + i;
        #pragma unroll
        for (int j = 0; j < 4; ++j) {
            const int n = nb + tx * 4 + j;
            const float v = fmaxf(acc[i][j] + bi[n], 0.f);
            h1cat[(size_t)m * 1024 + net * 512 + n] = f2bf(v);
        }
    }
}

// ---------------------------------------------------------------------------
// W1 (dimwise) [512 k][512 n] f32 -> W1p [512 n][512 k] bf16 (unmasked)
// ---------------------------------------------------------------------------
__global__ __launch_bounds__(256, 4)
void prep_w1_k(const float* __restrict__ W1, unsigned short* __restrict__ W1p)
{
    __shared__ float tile[32][33];
    const int tid = threadIdx.x;
    const int k0 = blockIdx.y * 32, n0 = blockIdx.x * 32;
    const int c = tid & 31, r4 = tid >> 5;
    #pragma unroll
    for (int i = 0; i < 4; ++i) {
        const int r = r4 * 4 + i;
        tile[r][c] = W1[(k0 + r) * 512 + n0 + c];
    }
    __syncthreads();
    #pragma unroll
    for (int i = 0; i < 4; ++i) {
        const int r = r4 * 4 + i;
        W1p[(n0 + r) * 512 + k0 + c] = f2bf(tile[c][r]);
    }
}

// ---------------------------------------------------------------------------
// W0 (dimwise) h-rows -> W0t[512 n][64 k] bf16 (W0t[n][k] = W0[2+k][n])
// ---------------------------------------------------------------------------
__global__ __launch_bounds__(256, 4)
void prep_w0t_k(const float* __restrict__ W0, unsigned short* __restrict__ W0t)
{
    const int idx = blockIdx.x * 256 + threadIdx.x;   // 0..32767
    const int n = idx & 511, k = idx >> 9;
    W0t[n * 64 + k] = f2bf(W0[(2 + k) * 512 + n]);
}

// ---------------------------------------------------------------------------
// MADE W1 masked+transposed: W1t[n 0..1023][k 0..511] bf16
// n<512 -> net0 (W1a), n>=512 -> net1 (W1b); mask: (k%127) <= ((n&511)%127)
// ---------------------------------------------------------------------------
__global__ __launch_bounds__(256, 4)
void prep_w1t_k(const float* __restrict__ W1a, const float* __restrict__ W1b,
                unsigned short* __restrict__ W1t)
{
    __shared__ float tile[32][33];
    const int tid = threadIdx.x;
    const int n0 = blockIdx.x * 32;      // 0..1023
    const int k0 = blockIdx.y * 32;      // 0..511
    const float* __restrict__ src = (n0 < 512) ? W1a : W1b;
    const int nrel0 = n0 & 511;
    const int c = tid & 31, r4 = tid >> 5;
    #pragma unroll
    for (int i = 0; i < 4; ++i) {
        const int r = r4 * 4 + i;        // k-offset
        tile[r][c] = src[(k0 + r) * 512 + nrel0 + c];
    }
    __syncthreads();
    #pragma unroll
    for (int i = 0; i < 4; ++i) {
        const int r = r4 * 4 + i;        // n-offset
        const int n = n0 + r;
        const int k = k0 + c;
        const bool keep = (k % 127) <= ((n & 511) % 127);
        W1t[(size_t)n * 512 + k] = keep ? f2bf(tile[c][r]) : (unsigned short)0;
    }
}

// ---------------------------------------------------------------------------
// MADE W2 masked+transposed: W2t[n 0..8191][k 0..1023] bf16
// k<512 -> net0 (W2a): keep = (k%127) < (n&127)
// k>=512 -> net1 (W2b): keep = ((k&511)%127) < 127-(n&127)
// ---------------------------------------------------------------------------
__global__ __launch_bounds__(256, 4)
void prep_w2t_k(const float* __restrict__ W2a, const float* __restrict__ W2b,
                unsigned short* __restrict__ W2t)
{
    __shared__ float tile[32][33];
    const int tid = threadIdx.x;
    const int n0 = blockIdx.x * 32;      // 0..8191
    const int k0 = blockIdx.y * 32;      // 0..1023 (tile within one net: 512%32==0)
    const float* __restrict__ src = (k0 < 512) ? W2a : W2b;
    const int krel0 = k0 & 511;
    const bool net1 = (k0 >= 512);
    const int c = tid & 31, r4 = tid >> 5;
    #pragma unroll
    for (int i = 0; i < 4; ++i) {
        const int r = r4 * 4 + i;        // k-offset
        tile[r][c] = src[(size_t)(krel0 + r) * 8192 + n0 + c];
    }
    __syncthreads();
    #pragma unroll
    for (int i = 0; i < 4; ++i) {
        const int r = r4 * 4 + i;        // n-offset
        const int n = n0 + r;
        const int k = k0 + c;
        const int km = (k & 511) % 127;
        const int dg = n & 127;
        const bool keep = net1 ? (km < 127 - dg) : (km < dg);
        W2t[(size_t)n * 1024 + k] = keep ? f2bf(tile[c][r]) : (unsigned short)0;
    }
}

// ---------------------------------------------------------------------------
// MADE layer 2, both nets: h2 = relu(h1 @ W1m + b). Barrier-free MFMA.
// Tile 64x64, 8 waves (4 wm x 2 wn), K=512, 16 steps. grid (16,16).
// ---------------------------------------------------------------------------
__global__ __launch_bounds__(512, 2)
void gemm2_k(const unsigned short* __restrict__ h1cat,
             const unsigned short* __restrict__ W1t,
             const float* __restrict__ ba, const float* __restrict__ bb,
             unsigned short* __restrict__ h2cat)
{
    const int tid = threadIdx.x;
    const int n0 = blockIdx.x * 64;      // global col
    const int m0 = blockIdx.y * 64;
    const int lane = tid & 63, w = tid >> 6;
    const int l15 = lane & 15, l16 = lane >> 4;
    const int wm = w & 3, wn = w >> 2;
    const int net = n0 >> 9;
    const float* __restrict__ bi = net ? bb : ba;

    const unsigned short* Ab = h1cat + (size_t)(m0 + wm * 16 + l15) * 1024 + net * 512 + l16 * 8;
    const unsigned short* Bb = W1t + (size_t)(n0 + wn * 32 + l15) * 512 + l16 * 8;

    f32x4 acc[2] = {};
    bf16x8 a0, b0[2], a1, b1[2];
    a0 = *(const bf16x8*)(Ab);
    b0[0] = *(const bf16x8*)(Bb);
    b0[1] = *(const bf16x8*)(Bb + 16 * 512);

    for (int s = 0; s < 16; ++s) {
        if (s < 15) {
            const int off = (s + 1) * 32;
            a1 = *(const bf16x8*)(Ab + off);
            b1[0] = *(const bf16x8*)(Bb + off);
            b1[1] = *(const bf16x8*)(Bb + 16 * 512 + off);
        }
        acc[0] = __builtin_amdgcn_mfma_f32_16x16x32_bf16(a0, b0[0], acc[0], 0, 0, 0);
        acc[1] = __builtin_amdgcn_mfma_f32_16x16x32_bf16(a0, b0[1], acc[1], 0, 0, 0);
        a0 = a1; b0[0] = b1[0]; b0[1] = b1[1];
    }

    #pragma unroll
    for (int nt = 0; nt < 2; ++nt) {
        const int n = n0 + wn * 32 + nt * 16 + l15;
        const float bv = bi[n & 511];
        #pragma unroll
        for (int e = 0; e < 4; ++e) {
            const float v = fmaxf(acc[nt][e] + bv, 0.f);
            h2cat[(size_t)(m0 + wm * 16 + l16 * 4 + e) * 1024 + n] = f2bf(v);
        }
    }
}

// ---------------------------------------------------------------------------
// MADE layer 3, both nets fused over K=1024: Hc = h2cat @ W2t^T + (b2a+b2b)
// Barrier-free MFMA, tile 128x128, 8 waves (4 wm x 2 wn), 32 steps. grid (64,8)
// ---------------------------------------------------------------------------
__global__ __launch_bounds__(512, 2)
void gemm3_k(const unsigned short* __restrict__ h2cat,
             const unsigned short* __restrict__ W2t,
             const float* __restrict__ ba, const float* __restrict__ bb,
             unsigned short* __restrict__ Hc)
{
    const int tid = threadIdx.x;
    const int n0 = blockIdx.x * 128, m0 = blockIdx.y * 128;
    const int lane = tid & 63, w = tid >> 6;
    const int l15 = lane & 15, l16 = lane >> 4;
    const int wm = w & 3, wn = w >> 2;

    const unsigned short* Ab = h2cat + (size_t)(m0 + wm * 32 + l15) * 1024 + l16 * 8;
    const unsigned short* Bb = W2t + (size_t)(n0 + wn * 64 + l15) * 1024 + l16 * 8;

    f32x4 acc[2][4] = {};
    bf16x8 a0[2], b0[4], a1[2], b1[4];
    #pragma unroll
    for (int mt = 0; mt < 2; ++mt) a0[mt] = *(const bf16x8*)(Ab + mt * 16 * 1024);
    #pragma unroll
    for (int nt = 0; nt < 4; ++nt) b0[nt] = *(const bf16x8*)(Bb + nt * 16 * 1024);

    for (int s = 0; s < 32; ++s) {
        if (s < 31) {
            const int off = (s + 1) * 32;
            #pragma unroll
            for (int mt = 0; mt < 2; ++mt) a1[mt] = *(const bf16x8*)(Ab + mt * 16 * 1024 + off);
            #pragma unroll
            for (int nt = 0; nt < 4; ++nt) b1[nt] = *(const bf16x8*)(Bb + nt * 16 * 1024 + off);
        }
        #pragma unroll
        for (int mt = 0; mt < 2; ++mt)
            #pragma unroll
            for (int nt = 0; nt < 4; ++nt)
                acc[mt][nt] = __builtin_amdgcn_mfma_f32_16x16x32_bf16(a0[mt], b0[nt], acc[mt][nt], 0, 0, 0);
        #pragma unroll
        for (int mt = 0; mt < 2; ++mt) a0[mt] = a1[mt];
        #pragma unroll
        for (int nt = 0; nt < 4; ++nt) b0[nt] = b1[nt];
    }

    #pragma unroll
    for (int nt = 0; nt < 4; ++nt) {
        const int n = n0 + wn * 64 + nt * 16 + l15;
        const float bsum = ba[n] + bb[n];
        #pragma unroll
        for (int mt = 0; mt < 2; ++mt) {
            const int mrow = m0 + wm * 32 + mt * 16 + l16 * 4;
            #pragma unroll
            for (int e = 0; e < 4; ++e)
                Hc[(size_t)(mrow + e) * 8192 + n] = f2bf(acc[mt][nt][e] + bsum);
        }
    }
}

// ---------------------------------------------------------------------------
// Fused dimwise MLP + exact JVP. Block = 32 rows x 512 threads (8 waves).
// Phase 1 (z1pre) MFMA from single bf16 Hc plane; phases 2/3 as r3; fast tanh.
// LDS: zA [0,34816) tA [34816,69632) Hstage [69632,73728) xbuf [73728,73856)
// ---------------------------------------------------------------------------
__global__ __launch_bounds__(512, 4)
void dimwise_k(const unsigned short* __restrict__ Hc,
               const float* __restrict__ x, const float* __restrict__ t,
               const unsigned short* __restrict__ W1p, const unsigned short* __restrict__ W0t,
               const float* __restrict__ W0, const float* __restrict__ b0,
               const float* __restrict__ b1,
               const float* __restrict__ W2, const float* __restrict__ b2,
               float* __restrict__ out)
{
    __shared__ __align__(16) char smem[73856];

    const int tid  = threadIdx.x;
    const int row0 = blockIdx.x * 32;
    const int b    = row0 >> 7;
    const int d0   = row0 & 127;

    const int lane = tid & 63;
    const int w    = tid >> 6;
    const int l15 = lane & 15, l16 = lane >> 4;

    // ---- phase 0: stage Hc tile [32 row][64 k] (XOR-swizzled) + x ----
    if (tid < 256) {
        const int k    = tid >> 2;            // 0..63
        const int part = tid & 3;             // d offset part*8
        const bf16x8 hv = *(const bf16x8*)(Hc + (size_t)b * 8192 + k * 128 + d0 + part * 8);
        #pragma unroll
        for (int j = 0; j < 8; ++j) {
            const int row = part * 8 + j;
            const int byte = 69632 + row * 128 + ((2 * k) ^ ((row & 7) << 4));
            *(unsigned short*)(smem + byte) = (unsigned short)hv[j];
        }
    }
    if (tid < 32) ((float*)(smem + 73728))[tid] = x[b * 128 + d0 + tid];
    __syncthreads();

    // ---- phase 1: z1pre via MFMA, rank-2 (t,x) + tanh epilogue ----
    f32x4 zacc[2][4] = {};
    #pragma unroll
    for (int ks = 0; ks < 2; ++ks) {
        bf16x8 af[2];
        #pragma unroll
        for (int mt = 0; mt < 2; ++mt) {
            const int row = mt * 16 + l15;
            const int inner = (ks * 64 + l16 * 16) ^ ((l15 & 7) << 4);
            af[mt] = *(const bf16x8*)(smem + 69632 + row * 128 + inner);
        }
        #pragma unroll
        for (int nt = 0; nt < 4; ++nt) {
            const int n = w * 64 + nt * 16 + l15;
            const bf16x8 bf = *(const bf16x8*)(W0t + n * 64 + ks * 32 + l16 * 8);
            #pragma unroll
            for (int mt = 0; mt < 2; ++mt)
                zacc[mt][nt] = __builtin_amdgcn_mfma_f32_16x16x32_bf16(af[mt], bf, zacc[mt][nt], 0, 0, 0);
        }
    }
    {
        const float tv = t[0];
        const float* xb = (const float*)(smem + 73728);
        float xm[2][4];
        #pragma unroll
        for (int mt = 0; mt < 2; ++mt)
            #pragma unroll
            for (int e = 0; e < 4; ++e)
                xm[mt][e] = xb[mt * 16 + l16 * 4 + e];
        #pragma unroll
        for (int nt = 0; nt < 4; ++nt) {
            const int n = w * 64 + nt * 16 + l15;
            const float b0n = b0[n];
            const float w00 = W0[n];
            const float w01 = W0[512 + n];
            const int kboff = (n >> 3) * 272 + (n & 7) * 2;
            #pragma unroll
            for (int mt = 0; mt < 2; ++mt)
                #pragma unroll
                for (int e = 0; e < 4; ++e) {
                    const float pre = zacc[mt][nt][e] + b0n + tv * w00 + xm[mt][e] * w01;
                    const float z = fast_tanh(pre);
                    const float s = (1.f - z * z) * w01;
                    const int off = mt * 17408 + kboff + (l16 * 4 + e) * 16;
                    *(unsigned short*)(smem + off)         = f2bf(z);
                    *(unsigned short*)(smem + 34816 + off) = f2bf(s);
                }
        }
    }
    __syncthreads();

    // ---- phase 2: layer-1 GEMM (bf16 MFMA), value + tangent paths ----
    const char* __restrict__ W1pc = (const char*)W1p;

    f32x4 accp[2][4] = {};
    f32x4 acct[2][4] = {};

    const int aoff0 = l15 * 16 + l16 * 272;

    bf16x8 za0[2], ta0[2], bf0[4];
    #pragma unroll
    for (int mt = 0; mt < 2; ++mt) {
        za0[mt] = *(const bf16x8*)(smem + mt * 17408 + aoff0);
        ta0[mt] = *(const bf16x8*)(smem + 34816 + mt * 17408 + aoff0);
    }
    #pragma unroll
    for (int nt = 0; nt < 4; ++nt) {
        const size_t boff = (size_t)(w * 64 + nt * 16 + l15) * 1024 + l16 * 16;
        bf0[nt] = *(const bf16x8*)(W1pc + boff);
    }

    for (int ks = 0; ks < 16; ++ks) {
        bf16x8 za1[2], ta1[2], bf1[4];
        if (ks < 15) {
            const int aoff = aoff0 + (ks + 1) * 1088;
            #pragma unroll
            for (int mt = 0; mt < 2; ++mt) {
                za1[mt] = *(const bf16x8*)(smem + mt * 17408 + aoff);
                ta1[mt] = *(const bf16x8*)(smem + 34816 + mt * 17408 + aoff);
            }
            #pragma unroll
            for (int nt = 0; nt < 4; ++nt) {
                const size_t boff = (size_t)(w * 64 + nt * 16 + l15) * 1024
                                  + (ks + 1) * 64 + l16 * 16;
                bf1[nt] = *(const bf16x8*)(W1pc + boff);
            }
        }
        #pragma unroll
        for (int mt = 0; mt < 2; ++mt)
            #pragma unroll
            for (int nt = 0; nt < 4; ++nt) {
                accp[mt][nt] = __builtin_amdgcn_mfma_f32_16x16x32_bf16(za0[mt], bf0[nt], accp[mt][nt], 0, 0, 0);
                acct[mt][nt] = __builtin_amdgcn_mfma_f32_16x16x32_bf16(ta0[mt], bf0[nt], acct[mt][nt], 0, 0, 0);
            }
        #pragma unroll
        for (int mt = 0; mt < 2; ++mt) { za0[mt] = za1[mt]; ta0[mt] = ta1[mt]; }
        #pragma unroll
        for (int nt = 0; nt < 4; ++nt) bf0[nt] = bf1[nt];
    }

    // ---- phase 3: tanh/JVP epilogue + 512->1 dot ----
    float py[2][4] = {}, pj[2][4] = {};
    #pragma unroll
    for (int nt = 0; nt < 4; ++nt) {
        const int n = w * 64 + nt * 16 + l15;
        const float b1v = b1[n];
        const float w2v = W2[n];
        #pragma unroll
        for (int mt = 0; mt < 2; ++mt)
            #pragma unroll
            for (int e = 0; e < 4; ++e) {
                const float z2  = fast_tanh(accp[mt][nt][e] + b1v);
                const float dz2 = (1.f - z2 * z2) * acct[mt][nt][e];
                py[mt][e] += z2  * w2v;
                pj[mt][e] += dz2 * w2v;
            }
    }
    #pragma unroll
    for (int off = 1; off < 16; off <<= 1)
        #pragma unroll
        for (int mt = 0; mt < 2; ++mt)
            #pragma unroll
            for (int e = 0; e < 4; ++e) {
                py[mt][e] += __shfl_xor(py[mt][e], off);
                pj[mt][e] += __shfl_xor(pj[mt][e], off);
            }

    __syncthreads();
    float* part = (float*)smem;         // [8 w][2 mt][16 row][2]
    if (l15 == 0) {
        const int q = l16;
        #pragma unroll
        for (int mt = 0; mt < 2; ++mt)
            #pragma unroll
            for (int e = 0; e < 4; ++e) {
                const int idx = ((w * 2 + mt) * 16 + 4 * q + e) * 2;
                part[idx]     = py[mt][e];
                part[idx + 1] = pj[mt][e];
            }
    }
    __syncthreads();
    if (tid < 64) {
        const int mt = tid >> 5, row = (tid >> 1) & 15, wh = tid & 1;
        float s = 0.f;
        #pragma unroll
        for (int w8 = 0; w8 < 8; ++w8)
            s += part[((w8 * 2 + mt) * 16 + row) * 2 + wh];
        const int grow = row0 + mt * 16 + row;
        if (wh == 0) out[grow] = s + b2[0];
        else         out[131072 + grow] = s;
    }
}

// ---------------------------------------------------------------------------
extern "C" void kernel_launch(void* const* d_in, const int* in_sizes, int n_in,
                              void* d_out, int out_size, void* d_ws, size_t ws_size,
                              hipStream_t stream)
{
    (void)in_sizes; (void)n_in; (void)out_size; (void)ws_size;

    const float* t     = (const float*)d_in[0];
    const float* x     = (const float*)d_in[1];
    const float* m1_W0 = (const float*)d_in[2];
    const float* m1_b0 = (const float*)d_in[3];
    const float* m1_W1 = (const float*)d_in[4];
    const float* m1_b1 = (const float*)d_in[5];
    const float* m1_W2 = (const float*)d_in[6];
    const float* m1_b2 = (const float*)d_in[7];
    const float* m2_W0 = (const float*)d_in[8];
    const float* m2_b0 = (const float*)d_in[9];
    const float* m2_W1 = (const float*)d_in[10];
    const float* m2_b1 = (const float*)d_in[11];
    const float* m2_W2 = (const float*)d_in[12];
    const float* m2_b2 = (const float*)d_in[13];
    const float* d_W0  = (const float*)d_in[14];
    const float* d_b0  = (const float*)d_in[15];
    const float* d_W1  = (const float*)d_in[16];
    const float* d_b1  = (const float*)d_in[17];
    const float* d_W2  = (const float*)d_in[18];
    const float* d_b2  = (const float*)d_in[19];

    // ws layout (peak 36.25 MB, same as r3's proven peak):
    // [0x0000000] W1p   512K  (live until dimwise)
    // [0x0080000] W0t    64K  (live until dimwise)
    // [0x0090000] h2cat   2M  (gemm2 -> gemm3)
    // [0x0290000] Hc     16M  (gemm3 -> dimwise)
    // [0x1290000] W2t    16M  (prep_w2t -> gemm3)
    //    h1cat (2M) and W1t (1M) overlay the W2t region: both are dead
    //    before prep_w2t_k runs (stream-serial).
    char* base = (char*)d_ws;
    unsigned short* W1p   = (unsigned short*)(base);
    unsigned short* W0t   = (unsigned short*)(base + 0x80000);
    unsigned short* h2cat = (unsigned short*)(base + 0x90000);
    unsigned short* Hc    = (unsigned short*)(base + 0x290000);
    unsigned short* W2t   = (unsigned short*)(base + 0x1290000);
    unsigned short* h1cat = (unsigned short*)(base + 0x1290000);  // overlay
    unsigned short* W1t   = (unsigned short*)(base + 0x1490000);  // overlay

    prep_w1_k<<<dim3(16, 16), dim3(256), 0, stream>>>(d_W1, W1p);
    prep_w0t_k<<<dim3(128), dim3(256), 0, stream>>>(d_W0, W0t);
    prep_w1t_k<<<dim3(32, 16), dim3(256), 0, stream>>>(m1_W1, m2_W1, W1t);

    made1_k<<<dim3(16, 16), dim3(256), 0, stream>>>(x, m1_W0, m2_W0, m1_b0, m2_b0, h1cat);
    gemm2_k<<<dim3(16, 16), dim3(512), 0, stream>>>(h1cat, W1t, m1_b1, m2_b1, h2cat);

    prep_w2t_k<<<dim3(256, 32), dim3(256), 0, stream>>>(m1_W2, m2_W2, W2t);
    gemm3_k<<<dim3(64, 8), dim3(512), 0, stream>>>(h2cat, W2t, m1_b2, m2_b2, Hc);

    dimwise_k<<<dim3(4096), dim3(512), 0, stream>>>(Hc, x, t, W1p, W0t,
                                                    d_W0, d_b0, d_b1, d_W2, d_b2,
                                                    (float*)d_out);
}

// Round 5
// 410.230 us; speedup vs baseline: 4.8327x; 1.0507x over previous
//
#include <hip/hip_runtime.h>
#include <math.h>

// B=1024, D=128, DH=64, H=512 ; rows = B*D = 131072
// Hc (bf16): [1024, 8192], Hc[b, k*128+d] = h[b,d,k]

typedef __attribute__((ext_vector_type(8))) short bf16x8;
typedef __attribute__((ext_vector_type(4))) float f32x4;

static __device__ __forceinline__ unsigned short f2bf(float f) {
    unsigned u = __builtin_bit_cast(unsigned, f);
    unsigned r = (u + 0x7FFFu + ((u >> 16) & 1u)) >> 16;
    return (unsigned short)r;
}

static __device__ __forceinline__ float fexp2(float x) {
#if __has_builtin(__builtin_amdgcn_exp2f)
    return __builtin_amdgcn_exp2f(x);
#else
    float r; asm("v_exp_f32 %0, %1" : "=v"(r) : "v"(x)); return r;
#endif
}
static __device__ __forceinline__ float frcp(float x) {
#if __has_builtin(__builtin_amdgcn_rcpf)
    return __builtin_amdgcn_rcpf(x);
#else
    float r; asm("v_rcp_f32 %0, %1" : "=v"(r) : "v"(x)); return r;
#endif
}
// tanh(x) = 1 - 2/(1+e^{2x}); exp2-based, ~1e-6 abs err, saturates correctly.
static __device__ __forceinline__ float fast_tanh(float x) {
    const float e = fexp2(x * 2.8853900817779268f);   // e^{2x}
    const float r = frcp(1.f + e);
    return __builtin_fmaf(-2.f, r, 1.f);
}

// ---------------------------------------------------------------------------
// MADE layer 1, both nets: x[1024,128] @ (W0 .* mask1) -> h1cat bf16 [1024][1024]
// ---------------------------------------------------------------------------
__global__ __launch_bounds__(256, 4)
void made1_k(const float* __restrict__ x,
             const float* __restrict__ Wn1, const float* __restrict__ Wn2,
             const float* __restrict__ bn1, const float* __restrict__ bn2,
             unsigned short* __restrict__ h1cat)
{
    __shared__ float As[16][68];
    __shared__ float Bs[16][68];

    const int tid = threadIdx.x;
    const int bn  = blockIdx.x;          // 0..15 : net = bn>>3
    const int bm  = blockIdx.y;          // 0..15
    const int net = bn >> 3;
    const int nb  = (bn & 7) * 64;
    const int tx = tid & 15, ty = tid >> 4;
    const int m_base = bm * 64;

    const float* __restrict__ W  = net ? Wn2 : Wn1;
    const float* __restrict__ bi = net ? bn2 : bn1;

    float acc[4][4] = {};

    for (int k0 = 0; k0 < 128; k0 += 16) {
        {
            const int m  = tid >> 2;
            const int kk = (tid & 3) * 4;
            const float4 a4 = *reinterpret_cast<const float4*>(&x[(size_t)(m_base + m) * 128 + k0 + kk]);
            As[kk + 0][m] = a4.x; As[kk + 1][m] = a4.y;
            As[kk + 2][m] = a4.z; As[kk + 3][m] = a4.w;
        }
        {
            const int kk = tid >> 4;
            const int nn = (tid & 15) * 4;
            const int gk = k0 + kk;
            const int gn = nb + nn;
            float4 b4 = *reinterpret_cast<const float4*>(&W[gk * 512 + gn]);
            float bv[4] = {b4.x, b4.y, b4.z, b4.w};
            #pragma unroll
            for (int j = 0; j < 4; ++j) {
                const int n = gn + j;
                const bool keep = net ? ((127 - gk) <= (n % 127)) : (gk <= (n % 127));
                Bs[kk][nn + j] = keep ? bv[j] : 0.f;
            }
        }
        __syncthreads();
        #pragma unroll
        for (int kk = 0; kk < 16; ++kk) {
            const float4 a4 = *reinterpret_cast<const float4*>(&As[kk][ty * 4]);
            const float4 b4 = *reinterpret_cast<const float4*>(&Bs[kk][tx * 4]);
            const float av[4] = {a4.x, a4.y, a4.z, a4.w};
            const float bv[4] = {b4.x, b4.y, b4.z, b4.w};
            #pragma unroll
            for (int i = 0; i < 4; ++i)
                #pragma unroll
                for (int j = 0; j < 4; ++j)
                    acc[i][j] += av[i] * bv[j];
        }
        __syncthreads();
    }

    #pragma unroll
    for (int i = 0; i < 4; ++i) {
        const int m = m_base + ty * 4 + i;
        #pragma unroll
        for (int j = 0; j < 4; ++j) {
            const int n = nb + tx * 4 + j;
            const float v = fmaxf(acc[i][j] + bi[n], 0.f);
            h1cat[(size_t)m * 1024 + net * 512 + n] = f2bf(v);
        }
    }
}

// ---------------------------------------------------------------------------
// W1 (dimwise) [512 k][512 n] f32 -> W1p [512 n][512 k] bf16 (unmasked)
// ---------------------------------------------------------------------------
__global__ __launch_bounds__(256, 4)
void prep_w1_k(const float* __restrict__ W1, unsigned short* __restrict__ W1p)
{
    __shared__ float tile[32][33];
    const int tid = threadIdx.x;
    const int k0 = blockIdx.y * 32, n0 = blockIdx.x * 32;
    const int c = tid & 31, r4 = tid >> 5;
    #pragma unroll
    for (int i = 0; i < 4; ++i) {
        const int r = r4 * 4 + i;
        tile[r][c] = W1[(k0 + r) * 512 + n0 + c];
    }
    __syncthreads();
    #pragma unroll
    for (int i = 0; i < 4; ++i) {
        const int r = r4 * 4 + i;
        W1p[(n0 + r) * 512 + k0 + c] = f2bf(tile[c][r]);
    }
}

// ---------------------------------------------------------------------------
// W0 (dimwise) h-rows -> W0t[512 n][64 k] bf16 (W0t[n][k] = W0[2+k][n])
// ---------------------------------------------------------------------------
__global__ __launch_bounds__(256, 4)
void prep_w0t_k(const float* __restrict__ W0, unsigned short* __restrict__ W0t)
{
    const int idx = blockIdx.x * 256 + threadIdx.x;   // 0..32767
    const int n = idx & 511, k = idx >> 9;
    W0t[n * 64 + k] = f2bf(W0[(2 + k) * 512 + n]);
}

// ---------------------------------------------------------------------------
// MADE W1 masked+transposed: W1t[n 0..1023][k 0..511] bf16
// ---------------------------------------------------------------------------
__global__ __launch_bounds__(256, 4)
void prep_w1t_k(const float* __restrict__ W1a, const float* __restrict__ W1b,
                unsigned short* __restrict__ W1t)
{
    __shared__ float tile[32][33];
    const int tid = threadIdx.x;
    const int n0 = blockIdx.x * 32;      // 0..1023
    const int k0 = blockIdx.y * 32;      // 0..511
    const float* __restrict__ src = (n0 < 512) ? W1a : W1b;
    const int nrel0 = n0 & 511;
    const int c = tid & 31, r4 = tid >> 5;
    #pragma unroll
    for (int i = 0; i < 4; ++i) {
        const int r = r4 * 4 + i;        // k-offset
        tile[r][c] = src[(k0 + r) * 512 + nrel0 + c];
    }
    __syncthreads();
    #pragma unroll
    for (int i = 0; i < 4; ++i) {
        const int r = r4 * 4 + i;        // n-offset
        const int n = n0 + r;
        const int k = k0 + c;
        const bool keep = (k % 127) <= ((n & 511) % 127);
        W1t[(size_t)n * 512 + k] = keep ? f2bf(tile[c][r]) : (unsigned short)0;
    }
}

// ---------------------------------------------------------------------------
// MADE W2 masked+transposed: W2t[n 0..8191][k 0..1023] bf16
// ---------------------------------------------------------------------------
__global__ __launch_bounds__(256, 4)
void prep_w2t_k(const float* __restrict__ W2a, const float* __restrict__ W2b,
                unsigned short* __restrict__ W2t)
{
    __shared__ float tile[32][33];
    const int tid = threadIdx.x;
    const int n0 = blockIdx.x * 32;      // 0..8191
    const int k0 = blockIdx.y * 32;      // 0..1023
    const float* __restrict__ src = (k0 < 512) ? W2a : W2b;
    const int krel0 = k0 & 511;
    const bool net1 = (k0 >= 512);
    const int c = tid & 31, r4 = tid >> 5;
    #pragma unroll
    for (int i = 0; i < 4; ++i) {
        const int r = r4 * 4 + i;        // k-offset
        tile[r][c] = src[(size_t)(krel0 + r) * 8192 + n0 + c];
    }
    __syncthreads();
    #pragma unroll
    for (int i = 0; i < 4; ++i) {
        const int r = r4 * 4 + i;        // n-offset
        const int n = n0 + r;
        const int k = k0 + c;
        const int km = (k & 511) % 127;
        const int dg = n & 127;
        const bool keep = net1 ? (km < 127 - dg) : (km < dg);
        W2t[(size_t)n * 1024 + k] = keep ? f2bf(tile[c][r]) : (unsigned short)0;
    }
}

// ---------------------------------------------------------------------------
// MADE layer 2: h2 = relu(h1 @ W1m + b). Barrier-free MFMA, tile 64x64.
// ---------------------------------------------------------------------------
__global__ __launch_bounds__(512, 2)
void gemm2_k(const unsigned short* __restrict__ h1cat,
             const unsigned short* __restrict__ W1t,
             const float* __restrict__ ba, const float* __restrict__ bb,
             unsigned short* __restrict__ h2cat)
{
    const int tid = threadIdx.x;
    const int n0 = blockIdx.x * 64;
    const int m0 = blockIdx.y * 64;
    const int lane = tid & 63, w = tid >> 6;
    const int l15 = lane & 15, l16 = lane >> 4;
    const int wm = w & 3, wn = w >> 2;
    const int net = n0 >> 9;
    const float* __restrict__ bi = net ? bb : ba;

    const unsigned short* Ab = h1cat + (size_t)(m0 + wm * 16 + l15) * 1024 + net * 512 + l16 * 8;
    const unsigned short* Bb = W1t + (size_t)(n0 + wn * 32 + l15) * 512 + l16 * 8;

    f32x4 acc[2] = {};
    bf16x8 a0, b0[2], a1, b1[2];
    a0 = *(const bf16x8*)(Ab);
    b0[0] = *(const bf16x8*)(Bb);
    b0[1] = *(const bf16x8*)(Bb + 16 * 512);

    #pragma unroll
    for (int s = 0; s < 15; ++s) {
        const int off = (s + 1) * 32;
        a1 = *(const bf16x8*)(Ab + off);
        b1[0] = *(const bf16x8*)(Bb + off);
        b1[1] = *(const bf16x8*)(Bb + 16 * 512 + off);
        acc[0] = __builtin_amdgcn_mfma_f32_16x16x32_bf16(a0, b0[0], acc[0], 0, 0, 0);
        acc[1] = __builtin_amdgcn_mfma_f32_16x16x32_bf16(a0, b0[1], acc[1], 0, 0, 0);
        a0 = a1; b0[0] = b1[0]; b0[1] = b1[1];
    }
    acc[0] = __builtin_amdgcn_mfma_f32_16x16x32_bf16(a0, b0[0], acc[0], 0, 0, 0);
    acc[1] = __builtin_amdgcn_mfma_f32_16x16x32_bf16(a0, b0[1], acc[1], 0, 0, 0);

    #pragma unroll
    for (int nt = 0; nt < 2; ++nt) {
        const int n = n0 + wn * 32 + nt * 16 + l15;
        const float bv = bi[n & 511];
        #pragma unroll
        for (int e = 0; e < 4; ++e) {
            const float v = fmaxf(acc[nt][e] + bv, 0.f);
            h2cat[(size_t)(m0 + wm * 16 + l16 * 4 + e) * 1024 + n] = f2bf(v);
        }
    }
}

// ---------------------------------------------------------------------------
// MADE layer 3, both nets fused over K=1024: Hc = h2cat @ W2t^T + (b2a+b2b)
// ---------------------------------------------------------------------------
__global__ __launch_bounds__(512, 2)
void gemm3_k(const unsigned short* __restrict__ h2cat,
             const unsigned short* __restrict__ W2t,
             const float* __restrict__ ba, const float* __restrict__ bb,
             unsigned short* __restrict__ Hc)
{
    const int tid = threadIdx.x;
    const int n0 = blockIdx.x * 128, m0 = blockIdx.y * 128;
    const int lane = tid & 63, w = tid >> 6;
    const int l15 = lane & 15, l16 = lane >> 4;
    const int wm = w & 3, wn = w >> 2;

    const unsigned short* Ab = h2cat + (size_t)(m0 + wm * 32 + l15) * 1024 + l16 * 8;
    const unsigned short* Bb = W2t + (size_t)(n0 + wn * 64 + l15) * 1024 + l16 * 8;

    f32x4 acc[2][4] = {};
    bf16x8 a0[2], b0[4], a1[2], b1[4];
    #pragma unroll
    for (int mt = 0; mt < 2; ++mt) a0[mt] = *(const bf16x8*)(Ab + mt * 16 * 1024);
    #pragma unroll
    for (int nt = 0; nt < 4; ++nt) b0[nt] = *(const bf16x8*)(Bb + nt * 16 * 1024);

    for (int s = 0; s < 32; ++s) {
        if (s < 31) {
            const int off = (s + 1) * 32;
            #pragma unroll
            for (int mt = 0; mt < 2; ++mt) a1[mt] = *(const bf16x8*)(Ab + mt * 16 * 1024 + off);
            #pragma unroll
            for (int nt = 0; nt < 4; ++nt) b1[nt] = *(const bf16x8*)(Bb + nt * 16 * 1024 + off);
        }
        #pragma unroll
        for (int mt = 0; mt < 2; ++mt)
            #pragma unroll
            for (int nt = 0; nt < 4; ++nt)
                acc[mt][nt] = __builtin_amdgcn_mfma_f32_16x16x32_bf16(a0[mt], b0[nt], acc[mt][nt], 0, 0, 0);
        #pragma unroll
        for (int mt = 0; mt < 2; ++mt) a0[mt] = a1[mt];
        #pragma unroll
        for (int nt = 0; nt < 4; ++nt) b0[nt] = b1[nt];
    }

    #pragma unroll
    for (int nt = 0; nt < 4; ++nt) {
        const int n = n0 + wn * 64 + nt * 16 + l15;
        const float bsum = ba[n] + bb[n];
        #pragma unroll
        for (int mt = 0; mt < 2; ++mt) {
            const int mrow = m0 + wm * 32 + mt * 16 + l16 * 4;
            #pragma unroll
            for (int e = 0; e < 4; ++e)
                Hc[(size_t)(mrow + e) * 8192 + n] = f2bf(acc[mt][nt][e] + bsum);
        }
    }
}

// ---------------------------------------------------------------------------
// Fused dimwise MLP + exact JVP. Block = 32 rows x 512 threads (8 waves).
// r5: XCD-swizzled bid, fully-unrolled phase 2 (peeled tail), hoisted scalars.
// LDS: zA [0,34816) tA [34816,69632) Hstage [69632,73728) xbuf [73728,73856)
// ---------------------------------------------------------------------------
__global__ __launch_bounds__(512, 4)
void dimwise_k(const unsigned short* __restrict__ Hc,
               const float* __restrict__ x, const float* __restrict__ t,
               const unsigned short* __restrict__ W1p, const unsigned short* __restrict__ W0t,
               const float* __restrict__ W0, const float* __restrict__ b0,
               const float* __restrict__ b1,
               const float* __restrict__ W2, const float* __restrict__ b2,
               float* __restrict__ out)
{
    __shared__ __align__(16) char smem[73856];

    const int tid  = threadIdx.x;
    // bijective XCD swizzle: all 4 d-blocks of a batch row land on one XCD,
    // and each XCD re-reads only ~256KB of Hc per round -> W1p stays L2-hot.
    const int bid  = (blockIdx.x & 7) * 512 + (blockIdx.x >> 3);
    const int row0 = bid * 32;
    const int b    = row0 >> 7;
    const int d0   = row0 & 127;

    const int lane = tid & 63;
    const int w    = tid >> 6;
    const int l15 = lane & 15, l16 = lane >> 4;

    // ---- hoisted phase-1 scalars (issue early; dead before phase 2) ----
    float b0n_r[4], w00_r[4], w01_r[4];
    #pragma unroll
    for (int nt = 0; nt < 4; ++nt) {
        const int n = w * 64 + nt * 16 + l15;
        b0n_r[nt] = b0[n];
        w00_r[nt] = W0[n];
        w01_r[nt] = W0[512 + n];
    }
    const float tv = t[0];

    // ---- phase 0: stage Hc tile [32 row][64 k] (XOR-swizzled) + x ----
    if (tid < 256) {
        const int k    = tid >> 2;            // 0..63
        const int part = tid & 3;             // d offset part*8
        const bf16x8 hv = *(const bf16x8*)(Hc + (size_t)b * 8192 + k * 128 + d0 + part * 8);
        #pragma unroll
        for (int j = 0; j < 8; ++j) {
            const int row = part * 8 + j;
            const int byte = 69632 + row * 128 + ((2 * k) ^ ((row & 7) << 4));
            *(unsigned short*)(smem + byte) = (unsigned short)hv[j];
        }
    }
    if (tid < 32) ((float*)(smem + 73728))[tid] = x[b * 128 + d0 + tid];
    __syncthreads();

    // ---- phase 1: z1pre via MFMA, rank-2 (t,x) + tanh epilogue ----
    f32x4 zacc[2][4] = {};
    #pragma unroll
    for (int ks = 0; ks < 2; ++ks) {
        bf16x8 af[2];
        #pragma unroll
        for (int mt = 0; mt < 2; ++mt) {
            const int row = mt * 16 + l15;
            const int inner = (ks * 64 + l16 * 16) ^ ((l15 & 7) << 4);
            af[mt] = *(const bf16x8*)(smem + 69632 + row * 128 + inner);
        }
        #pragma unroll
        for (int nt = 0; nt < 4; ++nt) {
            const int n = w * 64 + nt * 16 + l15;
            const bf16x8 bf = *(const bf16x8*)(W0t + n * 64 + ks * 32 + l16 * 8);
            #pragma unroll
            for (int mt = 0; mt < 2; ++mt)
                zacc[mt][nt] = __builtin_amdgcn_mfma_f32_16x16x32_bf16(af[mt], bf, zacc[mt][nt], 0, 0, 0);
        }
    }
    {
        const float* xb = (const float*)(smem + 73728);
        float xm[2][4];
        #pragma unroll
        for (int mt = 0; mt < 2; ++mt)
            #pragma unroll
            for (int e = 0; e < 4; ++e)
                xm[mt][e] = xb[mt * 16 + l16 * 4 + e];
        #pragma unroll
        for (int nt = 0; nt < 4; ++nt) {
            const int n = w * 64 + nt * 16 + l15;
            const int kboff = (n >> 3) * 272 + (n & 7) * 2;
            #pragma unroll
            for (int mt = 0; mt < 2; ++mt)
                #pragma unroll
                for (int e = 0; e < 4; ++e) {
                    const float pre = zacc[mt][nt][e] + b0n_r[nt] + tv * w00_r[nt] + xm[mt][e] * w01_r[nt];
                    const float z = fast_tanh(pre);
                    const float s = (1.f - z * z) * w01_r[nt];
                    const int off = mt * 17408 + kboff + (l16 * 4 + e) * 16;
                    *(unsigned short*)(smem + off)         = f2bf(z);
                    *(unsigned short*)(smem + 34816 + off) = f2bf(s);
                }
        }
    }
    __syncthreads();

    // ---- phase 2: layer-1 GEMM (bf16 MFMA), fully unrolled, peeled tail ----
    const char* __restrict__ W1pc = (const char*)W1p;

    f32x4 accp[2][4] = {};
    f32x4 acct[2][4] = {};

    const int aoff0 = l15 * 16 + l16 * 272;
    const char* __restrict__ Wb = W1pc + (size_t)(w * 64 + l15) * 1024 + l16 * 16;

    bf16x8 za0[2], ta0[2], bf0[4];
    #pragma unroll
    for (int mt = 0; mt < 2; ++mt) {
        za0[mt] = *(const bf16x8*)(smem + mt * 17408 + aoff0);
        ta0[mt] = *(const bf16x8*)(smem + 34816 + mt * 17408 + aoff0);
    }
    #pragma unroll
    for (int nt = 0; nt < 4; ++nt)
        bf0[nt] = *(const bf16x8*)(Wb + nt * 16 * 1024);

    #pragma unroll
    for (int ks = 0; ks < 15; ++ks) {
        bf16x8 za1[2], ta1[2], bf1[4];
        const int aoff = aoff0 + (ks + 1) * 1088;
        #pragma unroll
        for (int mt = 0; mt < 2; ++mt) {
            za1[mt] = *(const bf16x8*)(smem + mt * 17408 + aoff);
            ta1[mt] = *(const bf16x8*)(smem + 34816 + mt * 17408 + aoff);
        }
        #pragma unroll
        for (int nt = 0; nt < 4; ++nt)
            bf1[nt] = *(const bf16x8*)(Wb + nt * 16 * 1024 + (ks + 1) * 64);
        #pragma unroll
        for (int mt = 0; mt < 2; ++mt)
            #pragma unroll
            for (int nt = 0; nt < 4; ++nt) {
                accp[mt][nt] = __builtin_amdgcn_mfma_f32_16x16x32_bf16(za0[mt], bf0[nt], accp[mt][nt], 0, 0, 0);
                acct[mt][nt] = __builtin_amdgcn_mfma_f32_16x16x32_bf16(ta0[mt], bf0[nt], acct[mt][nt], 0, 0, 0);
            }
        #pragma unroll
        for (int mt = 0; mt < 2; ++mt) { za0[mt] = za1[mt]; ta0[mt] = ta1[mt]; }
        #pragma unroll
        for (int nt = 0; nt < 4; ++nt) bf0[nt] = bf1[nt];
    }
    #pragma unroll
    for (int mt = 0; mt < 2; ++mt)
        #pragma unroll
        for (int nt = 0; nt < 4; ++nt) {
            accp[mt][nt] = __builtin_amdgcn_mfma_f32_16x16x32_bf16(za0[mt], bf0[nt], accp[mt][nt], 0, 0, 0);
            acct[mt][nt] = __builtin_amdgcn_mfma_f32_16x16x32_bf16(ta0[mt], bf0[nt], acct[mt][nt], 0, 0, 0);
        }

    // ---- phase 3: tanh/JVP epilogue + 512->1 dot ----
    float py[2][4] = {}, pj[2][4] = {};
    #pragma unroll
    for (int nt = 0; nt < 4; ++nt) {
        const int n = w * 64 + nt * 16 + l15;
        const float b1v = b1[n];
        const float w2v = W2[n];
        #pragma unroll
        for (int mt = 0; mt < 2; ++mt)
            #pragma unroll
            for (int e = 0; e < 4; ++e) {
                const float z2  = fast_tanh(accp[mt][nt][e] + b1v);
                const float dz2 = (1.f - z2 * z2) * acct[mt][nt][e];
                py[mt][e] += z2  * w2v;
                pj[mt][e] += dz2 * w2v;
            }
    }
    #pragma unroll
    for (int off = 1; off < 16; off <<= 1)
        #pragma unroll
        for (int mt = 0; mt < 2; ++mt)
            #pragma unroll
            for (int e = 0; e < 4; ++e) {
                py[mt][e] += __shfl_xor(py[mt][e], off);
                pj[mt][e] += __shfl_xor(pj[mt][e], off);
            }

    __syncthreads();
    float* part = (float*)smem;         // [8 w][2 mt][16 row][2]
    if (l15 == 0) {
        const int q = l16;
        #pragma unroll
        for (int mt = 0; mt < 2; ++mt)
            #pragma unroll
            for (int e = 0; e < 4; ++e) {
                const int idx = ((w * 2 + mt) * 16 + 4 * q + e) * 2;
                part[idx]     = py[mt][e];
                part[idx + 1] = pj[mt][e];
            }
    }
    __syncthreads();
    if (tid < 64) {
        const int mt = tid >> 5, row = (tid >> 1) & 15, wh = tid & 1;
        float s = 0.f;
        #pragma unroll
        for (int w8 = 0; w8 < 8; ++w8)
            s += part[((w8 * 2 + mt) * 16 + row) * 2 + wh];
        const int grow = row0 + mt * 16 + row;
        if (wh == 0) out[grow] = s + b2[0];
        else         out[131072 + grow] = s;
    }
}

// ---------------------------------------------------------------------------
extern "C" void kernel_launch(void* const* d_in, const int* in_sizes, int n_in,
                              void* d_out, int out_size, void* d_ws, size_t ws_size,
                              hipStream_t stream)
{
    (void)in_sizes; (void)n_in; (void)out_size; (void)ws_size;

    const float* t     = (const float*)d_in[0];
    const float* x     = (const float*)d_in[1];
    const float* m1_W0 = (const float*)d_in[2];
    const float* m1_b0 = (const float*)d_in[3];
    const float* m1_W1 = (const float*)d_in[4];
    const float* m1_b1 = (const float*)d_in[5];
    const float* m1_W2 = (const float*)d_in[6];
    const float* m1_b2 = (const float*)d_in[7];
    const float* m2_W0 = (const float*)d_in[8];
    const float* m2_b0 = (const float*)d_in[9];
    const float* m2_W1 = (const float*)d_in[10];
    const float* m2_b1 = (const float*)d_in[11];
    const float* m2_W2 = (const float*)d_in[12];
    const float* m2_b2 = (const float*)d_in[13];
    const float* d_W0  = (const float*)d_in[14];
    const float* d_b0  = (const float*)d_in[15];
    const float* d_W1  = (const float*)d_in[16];
    const float* d_b1  = (const float*)d_in[17];
    const float* d_W2  = (const float*)d_in[18];
    const float* d_b2  = (const float*)d_in[19];

    // ws layout (peak 36.25 MB):
    // [0x0000000] W1p   512K ; [0x0080000] W0t 64K ; [0x0090000] h2cat 2M
    // [0x0290000] Hc 16M ; [0x1290000] W2t 16M (h1cat/W1t overlay W2t region)
    char* base = (char*)d_ws;
    unsigned short* W1p   = (unsigned short*)(base);
    unsigned short* W0t   = (unsigned short*)(base + 0x80000);
    unsigned short* h2cat = (unsigned short*)(base + 0x90000);
    unsigned short* Hc    = (unsigned short*)(base + 0x290000);
    unsigned short* W2t   = (unsigned short*)(base + 0x1290000);
    unsigned short* h1cat = (unsigned short*)(base + 0x1290000);  // overlay
    unsigned short* W1t   = (unsigned short*)(base + 0x1490000);  // overlay

    prep_w1_k<<<dim3(16, 16), dim3(256), 0, stream>>>(d_W1, W1p);
    prep_w0t_k<<<dim3(128), dim3(256), 0, stream>>>(d_W0, W0t);
    prep_w1t_k<<<dim3(32, 16), dim3(256), 0, stream>>>(m1_W1, m2_W1, W1t);

    made1_k<<<dim3(16, 16), dim3(256), 0, stream>>>(x, m1_W0, m2_W0, m1_b0, m2_b0, h1cat);
    gemm2_k<<<dim3(16, 16), dim3(512), 0, stream>>>(h1cat, W1t, m1_b1, m2_b1, h2cat);

    prep_w2t_k<<<dim3(256, 32), dim3(256), 0, stream>>>(m1_W2, m2_W2, W2t);
    gemm3_k<<<dim3(64, 8), dim3(512), 0, stream>>>(h2cat, W2t, m1_b2, m2_b2, Hc);

    dimwise_k<<<dim3(4096), dim3(512), 0, stream>>>(Hc, x, t, W1p, W0t,
                                                    d_W0, d_b0, d_b1, d_W2, d_b2,
                                                    (float*)d_out);
}